// Round 1
// baseline (1677.599 us; speedup 1.0000x reference)
//
#include <hip/hip_runtime.h>
#include <hip/hip_fp16.h>

// ---------------- model dims ----------------
// B=128, W=128, N=64, HID=150, L=2
// gates = 4*HID = 600 ; enc input D = 3*N = 192 ; dec input = 2*HID = 300

__device__ __forceinline__ float sigm(float x) {
    return 1.0f / (1.0f + __expf(-x));
}
__device__ __forceinline__ float tanhfast(float x) {
    return 2.0f / (1.0f + __expf(-2.0f * x)) - 1.0f;
}

// ---------------- copy x -> hs0 ----------------
__global__ void k_copy(const float* __restrict__ x, float* __restrict__ hs0) {
    int i = blockIdx.x * 256 + threadIdx.x;           // 262144 float4
    ((float4*)hs0)[i] = ((const float4*)x)[i];
}

// ---------------- conv branch: hs = relu(conv1d_k(x^T)+b)^T ----------------
// out[b,w,o] = relu( sum_t sum_i x[b, w+t-pad, i] * cw[o,i,t] + cb[o] )
template <int K>
__global__ void k_conv(const float* __restrict__ x, const float* __restrict__ cw,
                       const float* __restrict__ cb, float* __restrict__ dst) {
    extern __shared__ float S[];
    float* xl = S;                 // [128][64]
    float* wl = S + 8192;          // [(i*K+t)][66] -> + o
    const int pad = K >> 1;
    int b = blockIdx.x, tid = threadIdx.x;
    {   // stage x[b]
        const float4* src = (const float4*)(x + b * 8192);
        float4* d4 = (float4*)xl;
        for (int i = tid; i < 2048; i += 256) d4[i] = src[i];
    }
    {   // stage weights: global layout (o*64+i)*K + t
        int nw = 64 * 64 * K;
        for (int f = tid; f < nw; f += 256) {
            int o = f / (64 * K);
            int rem = f - o * 64 * K;
            int i = rem / K;
            int t = rem - i * K;
            wl[(i * K + t) * 66 + o] = cw[f];
        }
    }
    __syncthreads();
    int o = tid & 63, wq = tid >> 6;
    float bias = cb[o];
    for (int ww = 0; ww < 32; ++ww) {
        int w = wq * 32 + ww;
        float acc = bias;
        #pragma unroll
        for (int t = 0; t < K; ++t) {
            int wi = w + t - pad;
            if ((unsigned)wi < 128u) {
                const float* xr = xl + wi * 64;
                const float* wrow = wl + t * 66 + o;
                #pragma unroll
                for (int i4 = 0; i4 < 16; ++i4) {
                    float4 xv = *(const float4*)(xr + i4 * 4);
                    acc = fmaf(xv.x, wrow[(i4 * 4 + 0) * K * 66], acc);
                    acc = fmaf(xv.y, wrow[(i4 * 4 + 1) * K * 66], acc);
                    acc = fmaf(xv.z, wrow[(i4 * 4 + 2) * K * 66], acc);
                    acc = fmaf(xv.w, wrow[(i4 * 4 + 3) * K * 66], acc);
                }
            }
        }
        dst[b * 8192 + w * 64 + o] = fmaxf(acc, 0.f);
    }
}

// ---------------- one STGAT layer (all 3 branches), in-place residual ----------------
// grid (128 b, 3 branch), block 256, dyn LDS 135680 B
__global__ __launch_bounds__(256) void k_stgat(
    float* __restrict__ hs0, float* __restrict__ hs1, float* __restrict__ hs2,
    const float* __restrict__ gat_w, const float* __restrict__ gat_asrc,
    const float* __restrict__ gat_adst, const float* __restrict__ gat_b,
    const float* __restrict__ gcn_w, const float* __restrict__ gcn_b, int l) {
    extern __shared__ float S[];
    const int XPo = 0;               // xp [64][132]   (xp[n][w] = hs[b][w][n])
    const int GWo = 8448;            // phase1: gw [128][132]
    const int FTo = 8448;            // phase2+: fT [128][68]  (fT[w][n])
    const int ACo = 8448 + 8704;     // A [64][68], later cw [64][68]
    const int HRo = 25344;           // h [64][132], later hg [128][66]
    const int So = 33792;            // s[64]
    const int Do = 33856;            // d[64]

    int b = blockIdx.x, br = blockIdx.y, tid = threadIdx.x;
    float* hs = (br == 0 ? hs0 : (br == 1 ? hs1 : hs2)) + b * 8192;
    int wsel = br * 2 + l;
    const float* gw = gat_w + wsel * 16384;
    const float* asr = gat_asrc + wsel * 128;
    const float* ads = gat_adst + wsel * 128;
    const float* gb = gat_b + wsel * 128;
    const float* cwp = gcn_w + wsel * 4096;
    const float* cbp = gcn_b + wsel * 64;

    // stage xp (transposed input) and gw
    for (int f = tid; f < 8192; f += 256) {
        int w = f >> 6, n = f & 63;
        S[XPo + n * 132 + w] = hs[f];
    }
    for (int f = tid; f < 16384; f += 256) {
        int wo = f >> 7, k = f & 127;
        S[GWo + wo * 132 + k] = gw[f];
    }
    __syncthreads();

    int lane = tid & 63, wq = tid >> 6;
    // phase1: h[n][wo] = sum_w xp[n][w]*gw[wo][w]
    {
        float acc[32];
        #pragma unroll
        for (int j = 0; j < 32; ++j) acc[j] = 0.f;
        const float* xpr = &S[XPo + lane * 132];
        const float* gwb = &S[GWo + (wq * 32) * 132];
        for (int k4 = 0; k4 < 32; ++k4) {
            float4 xv = *(const float4*)(xpr + k4 * 4);
            #pragma unroll
            for (int j = 0; j < 32; ++j) {
                float4 gv = *(const float4*)(gwb + j * 132 + k4 * 4);
                acc[j] = fmaf(xv.x, gv.x, acc[j]);
                acc[j] = fmaf(xv.y, gv.y, acc[j]);
                acc[j] = fmaf(xv.z, gv.z, acc[j]);
                acc[j] = fmaf(xv.w, gv.w, acc[j]);
            }
        }
        float* hrow = &S[HRo + lane * 132 + wq * 32];
        #pragma unroll
        for (int j = 0; j < 32; ++j) hrow[j] = acc[j];
    }
    __syncthreads();
    // phase1b: s[i] = h[i].asrc ; d[i] = h[i].adst
    if (tid < 128) {
        int i = tid & 63;
        const float* av = (tid < 64) ? asr : ads;
        const float* hr = &S[HRo + i * 132];
        float acc = 0.f;
        for (int k4 = 0; k4 < 32; ++k4) {
            float4 hv = *(const float4*)(hr + k4 * 4);
            float4 aw = *(const float4*)(av + k4 * 4);
            acc = fmaf(hv.x, aw.x, acc);
            acc = fmaf(hv.y, aw.y, acc);
            acc = fmaf(hv.z, aw.z, acc);
            acc = fmaf(hv.w, aw.w, acc);
        }
        S[(tid < 64 ? So : Do) + i] = acc;
    }
    __syncthreads();
    // phase2a: A[j][i] = softmax_i( lrelu(s_i + d_j) )
    if (tid < 64) {
        float dj = S[Do + tid];
        float mx = -1e30f;
        for (int i = 0; i < 64; ++i) {
            float e = S[So + i] + dj;
            e = (e > 0.f) ? e : 0.2f * e;
            mx = fmaxf(mx, e);
        }
        float sum = 0.f;
        float* arow = &S[ACo + tid * 68];
        for (int i = 0; i < 64; ++i) {
            float e = S[So + i] + dj;
            e = (e > 0.f) ? e : 0.2f * e;
            float ex = __expf(e - mx);
            arow[i] = ex;
            sum += ex;
        }
        float rinv = 1.f / sum;
        for (int i = 0; i < 64; ++i) arow[i] *= rinv;
    }
    __syncthreads();
    // phase2b: f[n][w] = relu(sum_i A[n][i]*h[i][w] + gb[w]) stored transposed fT[w][n]
    {
        float acc[32];
        #pragma unroll
        for (int j = 0; j < 32; ++j) acc[j] = 0.f;
        const float* arow = &S[ACo + lane * 68];
        for (int i = 0; i < 64; ++i) {
            float a = arow[i];
            const float* hr = &S[HRo + i * 132 + wq * 32];
            #pragma unroll
            for (int w4 = 0; w4 < 8; ++w4) {
                float4 hv = *(const float4*)(hr + w4 * 4);
                acc[w4 * 4 + 0] = fmaf(a, hv.x, acc[w4 * 4 + 0]);
                acc[w4 * 4 + 1] = fmaf(a, hv.y, acc[w4 * 4 + 1]);
                acc[w4 * 4 + 2] = fmaf(a, hv.z, acc[w4 * 4 + 2]);
                acc[w4 * 4 + 3] = fmaf(a, hv.w, acc[w4 * 4 + 3]);
            }
        }
        #pragma unroll
        for (int w4 = 0; w4 < 8; ++w4) {
            float4 gv = *(const float4*)(gb + wq * 32 + w4 * 4);
            int wbase = wq * 32 + w4 * 4;
            S[FTo + (wbase + 0) * 68 + lane] = fmaxf(acc[w4 * 4 + 0] + gv.x, 0.f);
            S[FTo + (wbase + 1) * 68 + lane] = fmaxf(acc[w4 * 4 + 1] + gv.y, 0.f);
            S[FTo + (wbase + 2) * 68 + lane] = fmaxf(acc[w4 * 4 + 2] + gv.z, 0.f);
            S[FTo + (wbase + 3) * 68 + lane] = fmaxf(acc[w4 * 4 + 3] + gv.w, 0.f);
        }
    }
    __syncthreads();
    // phase3a: stage gcn weights (over A, which is dead)
    for (int f = tid; f < 4096; f += 256) {
        int c = f >> 6, k = f & 63;
        S[ACo + c * 68 + k] = cwp[f];
    }
    __syncthreads();
    // phase3b: hg[w][c] = sum_k fT[w][k]*cw[c][k]
    {
        float acc[32];
        #pragma unroll
        for (int j = 0; j < 32; ++j) acc[j] = 0.f;
        const float* cwr = &S[ACo + lane * 68];
        for (int k4 = 0; k4 < 16; ++k4) {
            float4 cv = *(const float4*)(cwr + k4 * 4);
            const float* ftb = &S[FTo + (wq * 32) * 68 + k4 * 4];
            #pragma unroll
            for (int w = 0; w < 32; ++w) {
                float4 fv = *(const float4*)(ftb + w * 68);
                acc[w] = fmaf(cv.x, fv.x, acc[w]);
                acc[w] = fmaf(cv.y, fv.y, acc[w]);
                acc[w] = fmaf(cv.z, fv.z, acc[w]);
                acc[w] = fmaf(cv.w, fv.w, acc[w]);
            }
        }
        #pragma unroll
        for (int w = 0; w < 32; ++w) S[HRo + (wq * 32 + w) * 66 + lane] = acc[w];
    }
    __syncthreads();
    // phase3c: per-column prefix scan with dinv = 1/sqrt(w+1), +bias, relu (in place)
    if (tid < 64) {
        int c = tid;
        float cbv = cbp[c];
        float run = 0.f;
        for (int w = 0; w < 128; ++w) {
            float dv = rsqrtf((float)(w + 1));
            run = fmaf(dv, S[HRo + w * 66 + c], run);
            float tv = fmaf(dv, run, cbv);
            S[HRo + w * 66 + c] = fmaxf(tv, 0.f);
        }
    }
    __syncthreads();
    // phase3d: permuted residual write: hs[b][a][cc] = xp[cc][a] + t_flat[cc*128+a]
    {
        int cc = tid & 63, rr = tid >> 6;
        for (int ai = 0; ai < 32; ++ai) {
            int a = ai * 4 + rr;
            int idx = cc * 128 + a;
            int w = idx >> 6, n = idx & 63;
            hs[a * 64 + cc] = S[HRo + w * 66 + n] + S[XPo + cc * 132 + a];
        }
    }
}

// ---------------- encoder input GEMM (dir0 full): gx0[b][t][g] = h[b,t]@Wih0^T + bias0 ----------------
// grid (128 b, 10 gtile), block 256
__global__ __launch_bounds__(256) void k_encgemm(
    const float* __restrict__ hs0, const float* __restrict__ hs1, const float* __restrict__ hs2,
    const float* __restrict__ wih, const float* __restrict__ bih, const float* __restrict__ bhh,
    float* __restrict__ gx0) {
    __shared__ __align__(16) float At[32 * 132];
    __shared__ __align__(16) float Bt[32 * 68];
    int b = blockIdx.x, ny = blockIdx.y, tid = threadIdx.x;
    int g0 = ny * 64;
    int ty = tid >> 4, tx = tid & 15;
    float acc[8][4];
    #pragma unroll
    for (int r = 0; r < 8; ++r)
        #pragma unroll
        for (int c = 0; c < 4; ++c) acc[r][c] = 0.f;
    const float* hsb[3] = {hs0 + b * 8192, hs1 + b * 8192, hs2 + b * 8192};
    for (int kc = 0; kc < 6; ++kc) {
        const float* src = hsb[kc >> 1] + (kc & 1) * 32;
        for (int f = tid; f < 4096; f += 256) {
            int t = f >> 5, kk = f & 31;
            At[kk * 132 + t] = src[t * 64 + kk];
        }
        for (int f = tid; f < 2048; f += 256) {
            int gg = f >> 5, kk = f & 31;
            int g = g0 + gg;
            Bt[kk * 68 + gg] = (g < 600) ? wih[g * 192 + kc * 32 + kk] : 0.f;
        }
        __syncthreads();
        #pragma unroll 8
        for (int kk = 0; kk < 32; ++kk) {
            float a[8], bb[4];
            *(float4*)&a[0] = *(const float4*)&At[kk * 132 + ty * 8];
            *(float4*)&a[4] = *(const float4*)&At[kk * 132 + ty * 8 + 4];
            *(float4*)&bb[0] = *(const float4*)&Bt[kk * 68 + tx * 4];
            #pragma unroll
            for (int r = 0; r < 8; ++r)
                #pragma unroll
                for (int c = 0; c < 4; ++c) acc[r][c] = fmaf(a[r], bb[c], acc[r][c]);
        }
        __syncthreads();
    }
    for (int r = 0; r < 8; ++r) {
        int t = ty * 8 + r;
        for (int c = 0; c < 4; ++c) {
            int g = g0 + tx * 4 + c;
            if (g < 600) gx0[(b * 128 + t) * 600 + g] = acc[r][c] + bih[g] + bhh[g];
        }
    }
}

// ---------------- encoder dir1 gates at t=127 only ----------------
__global__ void k_encgx1(const float* __restrict__ hs0, const float* __restrict__ hs1,
                         const float* __restrict__ hs2, const float* __restrict__ wih,
                         const float* __restrict__ bih, const float* __restrict__ bhh,
                         float* __restrict__ gx1) {
    __shared__ __align__(16) float sh[192];
    int b = blockIdx.x, tid = threadIdx.x;
    if (tid < 192) {
        const float* src = (tid < 64 ? hs0 : (tid < 128 ? hs1 : hs2));
        sh[tid] = src[b * 8192 + 127 * 64 + (tid & 63)];
    }
    __syncthreads();
    const float* w1 = wih + 600 * 192;
    for (int g = tid; g < 600; g += 256) {
        float acc = bih[600 + g] + bhh[600 + g];
        const float4* wr = (const float4*)(w1 + g * 192);
        #pragma unroll 8
        for (int q = 0; q < 48; ++q) {
            float4 wv = wr[q];
            float4 hv = *(const float4*)&sh[q * 4];
            acc = fmaf(wv.x, hv.x, acc);
            acc = fmaf(wv.y, hv.y, acc);
            acc = fmaf(wv.z, hv.z, acc);
            acc = fmaf(wv.w, hv.w, acc);
        }
        gx1[b * 600 + g] = acc;
    }
}

// ---------------- prefix sums of dec_wih rows: PT[k][dg], k=0..300 ----------------
__global__ void k_ptpref(const float* __restrict__ dwih, float* __restrict__ PT) {
    int dg = blockIdx.x * 256 + threadIdx.x;
    if (dg >= 1200) return;
    const float* wr = dwih + dg * 300;
    float run = 0.f;
    PT[dg] = 0.f;
    for (int k = 0; k < 300; ++k) {
        run += wr[k];
        PT[(k + 1) * 1200 + dg] = run;
    }
}

// ---------------- encoder LSTM: bid<128 full fwd scan, bid>=128 single bwd step ----------------
__global__ __launch_bounds__(640) void k_enclstm(const float* __restrict__ gx0,
                                                 const float* __restrict__ gx1,
                                                 const float* __restrict__ whh,
                                                 float* __restrict__ h_end) {
    __shared__ __align__(16) float shh[152];
    __shared__ __align__(16) float sact[600];
    int bid = blockIdx.x, g = threadIdx.x;
    bool on = g < 600;
    if (bid >= 128) {  // one bwd step from zero state on x_{127}
        int b = bid - 128;
        if (on) {
            float a = gx1[b * 600 + g];
            sact[g] = (g >= 300 && g < 450) ? tanhfast(a) : sigm(a);
        }
        __syncthreads();
        if (g < 150) {
            float c = sact[g] * sact[300 + g];
            h_end[b * 300 + 150 + g] = sact[450 + g] * tanhfast(c);
        }
        return;
    }
    int b = bid;
    __half2 wpk[76];
    if (on) {
        const float* wr = whh + g * 150;
        #pragma unroll
        for (int q = 0; q < 37; ++q)
            wpk[2 * q] = __floats2half2_rn(wr[q * 4 + 0], wr[q * 4 + 1]),
            wpk[2 * q + 1] = __floats2half2_rn(wr[q * 4 + 2], wr[q * 4 + 3]);
        wpk[74] = __floats2half2_rn(wr[148], wr[149]);
        wpk[75] = __floats2half2_rn(0.f, 0.f);
    } else {
        #pragma unroll
        for (int q = 0; q < 76; ++q) wpk[q] = __floats2half2_rn(0.f, 0.f);
    }
    for (int i = g; i < 152; i += 640) shh[i] = 0.f;
    float c = 0.f;
    float xt = on ? gx0[(b * 128) * 600 + g] : 0.f;
    __syncthreads();
    for (int t = 0; t < 128; ++t) {
        float xnx = (on && t < 127) ? gx0[(b * 128 + t + 1) * 600 + g] : 0.f;
        if (on) {
            float acc = xt;
            #pragma unroll
            for (int q = 0; q < 38; ++q) {
                float4 hv = *(const float4*)&shh[q * 4];
                __half2 wa = wpk[2 * q], wb = wpk[2 * q + 1];
                acc = fmaf(__half2float(__low2half(wa)), hv.x, acc);
                acc = fmaf(__half2float(__high2half(wa)), hv.y, acc);
                acc = fmaf(__half2float(__low2half(wb)), hv.z, acc);
                acc = fmaf(__half2float(__high2half(wb)), hv.w, acc);
            }
            sact[g] = (g >= 300 && g < 450) ? tanhfast(acc) : sigm(acc);
        }
        __syncthreads();
        if (g < 150) {
            c = fmaf(sact[150 + g], c, sact[g] * sact[300 + g]);
            float hn = sact[450 + g] * tanhfast(c);
            shh[g] = hn;
            if (t == 127) h_end[b * 300 + g] = hn;
        }
        xt = xnx;
        __syncthreads();
    }
}

// ---------------- decoder LSTM (both dirs), x-part from h_end via PT segments ----------------
__global__ __launch_bounds__(640) void k_declstm(const float* __restrict__ PT,
                                                 const float* __restrict__ hend,
                                                 const float* __restrict__ whh_all,
                                                 const float* __restrict__ bih,
                                                 const float* __restrict__ bhh,
                                                 float* __restrict__ dec_out) {
    __shared__ __align__(16) float she[304];
    __shared__ __align__(16) float shh[152];
    __shared__ __align__(16) float sact[600];
    int dir = blockIdx.x >> 7, b = blockIdx.x & 127;
    int g = threadIdx.x;
    bool on = g < 600;
    int dg = dir * 600 + g;
    __half2 wpk[76];
    if (on) {
        const float* wr = whh_all + dir * 90000 + g * 150;
        #pragma unroll
        for (int q = 0; q < 37; ++q)
            wpk[2 * q] = __floats2half2_rn(wr[q * 4 + 0], wr[q * 4 + 1]),
            wpk[2 * q + 1] = __floats2half2_rn(wr[q * 4 + 2], wr[q * 4 + 3]);
        wpk[74] = __floats2half2_rn(wr[148], wr[149]);
        wpk[75] = __floats2half2_rn(0.f, 0.f);
    } else {
        #pragma unroll
        for (int q = 0; q < 76; ++q) wpk[q] = __floats2half2_rn(0.f, 0.f);
    }
    float bias = on ? (bih[dg] + bhh[dg]) : 0.f;
    for (int i = g; i < 304; i += 640) she[i] = (i < 300) ? hend[b * 300 + i] : 0.f;
    for (int i = g; i < 152; i += 640) shh[i] = 0.f;
    float c = 0.f;
    __syncthreads();
    for (int s = 0; s < 128; ++s) {
        int t = dir ? (127 - s) : s;
        if (on) {
            float acc = bias;
            int base = t * 300;
            int j0 = base >> 7;
            int ke1 = (j0 + 1) * 128 - base;           // in [1,128]
            int ke2 = ke1 + 128; ke2 = ke2 > 300 ? 300 : ke2;
            int ke3 = ke1 + 256; ke3 = ke3 > 300 ? 300 : ke3;
            float p1 = PT[ke1 * 1200 + dg];
            float p2 = PT[ke2 * 1200 + dg];
            float p3 = PT[ke3 * 1200 + dg];
            float p4 = PT[300 * 1200 + dg];
            acc = fmaf(she[j0], p1, acc);
            acc = fmaf(she[j0 + 1], p2 - p1, acc);
            acc = fmaf(she[j0 + 2], p3 - p2, acc);
            acc = fmaf(she[j0 + 3], p4 - p3, acc);
            #pragma unroll
            for (int q = 0; q < 38; ++q) {
                float4 hv = *(const float4*)&shh[q * 4];
                __half2 wa = wpk[2 * q], wb = wpk[2 * q + 1];
                acc = fmaf(__half2float(__low2half(wa)), hv.x, acc);
                acc = fmaf(__half2float(__high2half(wa)), hv.y, acc);
                acc = fmaf(__half2float(__low2half(wb)), hv.z, acc);
                acc = fmaf(__half2float(__high2half(wb)), hv.w, acc);
            }
            sact[g] = (g >= 300 && g < 450) ? tanhfast(acc) : sigm(acc);
        }
        __syncthreads();
        if (g < 150) {
            c = fmaf(sact[150 + g], c, sact[g] * sact[300 + g]);
            float hn = sact[450 + g] * tanhfast(c);
            shh[g] = hn;
            dec_out[(b * 128 + t) * 300 + dir * 150 + g] = hn;
        }
        __syncthreads();
    }
}

// ---------------- final: out = dec @ fc_w^T + fc_b ----------------
__global__ __launch_bounds__(256) void k_fingemm(const float* __restrict__ dec,
                                                 const float* __restrict__ fw,
                                                 const float* __restrict__ fb,
                                                 float* __restrict__ out) {
    __shared__ __align__(16) float AsT[32 * 68];
    __shared__ __align__(16) float FwT[32 * 68];
    int r0 = blockIdx.x * 64, tid = threadIdx.x;
    int ty = tid >> 4, tx = tid & 15;
    float acc[4][4];
    #pragma unroll
    for (int r = 0; r < 4; ++r)
        #pragma unroll
        for (int c = 0; c < 4; ++c) acc[r][c] = 0.f;
    for (int kc = 0; kc < 10; ++kc) {
        int k0 = kc * 32;
        for (int f = tid; f < 2048; f += 256) {
            int m = f >> 5, kk = f & 31;
            int k = k0 + kk;
            AsT[kk * 68 + m] = (k < 300) ? dec[(r0 + m) * 300 + k] : 0.f;
        }
        for (int f = tid; f < 2048; f += 256) {
            int n = f >> 5, kk = f & 31;
            int k = k0 + kk;
            FwT[kk * 68 + n] = (k < 300) ? fw[n * 300 + k] : 0.f;
        }
        __syncthreads();
        #pragma unroll 8
        for (int kk = 0; kk < 32; ++kk) {
            float a[4], w[4];
            *(float4*)&a[0] = *(const float4*)&AsT[kk * 68 + ty * 4];
            *(float4*)&w[0] = *(const float4*)&FwT[kk * 68 + tx * 4];
            #pragma unroll
            for (int r = 0; r < 4; ++r)
                #pragma unroll
                for (int c = 0; c < 4; ++c) acc[r][c] = fmaf(a[r], w[c], acc[r][c]);
        }
        __syncthreads();
    }
    for (int r = 0; r < 4; ++r) {
        int m = r0 + ty * 4 + r;
        float4 o4;
        o4.x = acc[r][0] + fb[tx * 4 + 0];
        o4.y = acc[r][1] + fb[tx * 4 + 1];
        o4.z = acc[r][2] + fb[tx * 4 + 2];
        o4.w = acc[r][3] + fb[tx * 4 + 3];
        *(float4*)&out[m * 64 + tx * 4] = o4;
    }
}

// ---------------- host launcher ----------------
extern "C" void kernel_launch(void* const* d_in, const int* in_sizes, int n_in,
                              void* d_out, int out_size, void* d_ws, size_t ws_size,
                              hipStream_t stream) {
    const float* x = (const float*)d_in[0];
    const float* c2w = (const float*)d_in[3];
    const float* c2b = (const float*)d_in[4];
    const float* c3w = (const float*)d_in[5];
    const float* c3b = (const float*)d_in[6];
    const float* gatw = (const float*)d_in[7];
    const float* gatas = (const float*)d_in[8];
    const float* gatad = (const float*)d_in[9];
    const float* gatb = (const float*)d_in[10];
    const float* gcnw = (const float*)d_in[11];
    const float* gcnb = (const float*)d_in[12];
    const float* lwih = (const float*)d_in[13];
    const float* lwhh = (const float*)d_in[14];
    const float* lbih = (const float*)d_in[15];
    const float* lbhh = (const float*)d_in[16];
    const float* dwih = (const float*)d_in[17];
    const float* dwhh = (const float*)d_in[18];
    const float* dbih = (const float*)d_in[19];
    const float* dbhh = (const float*)d_in[20];
    const float* fcw = (const float*)d_in[21];
    const float* fcb = (const float*)d_in[22];
    float* out = (float*)d_out;
    float* ws = (float*)d_ws;

    float* hs0 = ws;                    // 1,048,576
    float* hs1 = ws + 1048576;          // 1,048,576
    float* hs2 = ws + 2097152;          // 1,048,576
    float* gx0 = ws + 3145728;          // 9,830,400
    float* gx1 = ws + 12976128;         // 76,800
    float* hend = ws + 13052928;        // 38,400
    float* PT = ws + 13091328;          // 361,200
    float* dec = ws + 13452528;         // 4,915,200   (end 18,367,728 floats ~ 70 MiB)

    k_copy<<<1024, 256, 0, stream>>>(x, hs0);
    k_conv<5><<<128, 256, (8192 + 64 * 5 * 66) * 4, stream>>>(x, c2w, c2b, hs1);
    k_conv<7><<<128, 256, (8192 + 64 * 7 * 66) * 4, stream>>>(x, c3w, c3b, hs2);
    for (int l = 0; l < 2; ++l)
        k_stgat<<<dim3(128, 3), 256, 33920 * 4, stream>>>(hs0, hs1, hs2, gatw, gatas,
                                                          gatad, gatb, gcnw, gcnb, l);
    k_encgemm<<<dim3(128, 10), 256, 0, stream>>>(hs0, hs1, hs2, lwih, lbih, lbhh, gx0);
    k_encgx1<<<128, 256, 0, stream>>>(hs0, hs1, hs2, lwih, lbih, lbhh, gx1);
    k_ptpref<<<5, 256, 0, stream>>>(dwih, PT);
    k_enclstm<<<256, 640, 0, stream>>>(gx0, gx1, lwhh, hend);
    k_declstm<<<256, 640, 0, stream>>>(PT, hend, dwhh, dbih, dbhh, dec);
    k_fingemm<<<256, 256, 0, stream>>>(dec, fcw, fcb, out);
}

// Round 2
// 1051.998 us; speedup vs baseline: 1.5947x; 1.5947x over previous
//
#include <hip/hip_runtime.h>
#include <hip/hip_fp16.h>

// ---------------- model dims ----------------
// B=128, W=128, N=64, HID=150, L=2
// gates = 4*HID = 600 ; enc input D = 3*N = 192 ; dec input = 2*HID = 300

typedef _Float16 v2h __attribute__((ext_vector_type(2)));

__device__ __forceinline__ float sigm(float x) {
    return 1.0f / (1.0f + __expf(-x));
}
__device__ __forceinline__ float tanhfast(float x) {
    return 2.0f / (1.0f + __expf(-2.0f * x)) - 1.0f;
}
__device__ __forceinline__ v2h pk2(float a, float b) {
    v2h r; r[0] = (_Float16)a; r[1] = (_Float16)b; return r;
}
__device__ __forceinline__ float fdot2(v2h a, v2h b, float c) {
#if __has_builtin(__builtin_amdgcn_fdot2)
    return __builtin_amdgcn_fdot2(a, b, c, false);
#else
    return c + (float)a[0] * (float)b[0] + (float)a[1] * (float)b[1];
#endif
}

// ---------------- copy x -> hs0 ----------------
__global__ void k_copy(const float* __restrict__ x, float* __restrict__ hs0) {
    int i = blockIdx.x * 256 + threadIdx.x;           // 262144 float4
    ((float4*)hs0)[i] = ((const float4*)x)[i];
}

// ---------------- conv branches (merged): out[b,w,o]=relu(sum_{t,i} x[b,w+t-pad,i]*cw[o,i,t]+cb[o]) ----------------
// grid (128 b, 2 wh, 2 br), block 256. Register tile 4w x 4o, float4 dot over i.
__global__ __launch_bounds__(256) void k_conv2(
    const float* __restrict__ x,
    const float* __restrict__ cw5, const float* __restrict__ cb5,
    const float* __restrict__ cw7, const float* __restrict__ cb7,
    float* __restrict__ hs1, float* __restrict__ hs2) {
    extern __shared__ float S[];
    float* xt = S;              // [70][68] rows ww=0..69 <-> global w' = w0-3+ww
    float* wl = S + 70 * 68;    // [(t*16+i4)*256 + o*4 + j] = cw[o][i4*4+j][t]
    int b = blockIdx.x, wh = blockIdx.y, br = blockIdx.z;
    int K = br ? 7 : 5;
    const float* cw = br ? cw7 : cw5;
    const float* cb = br ? cb7 : cb5;
    float* dst = br ? hs2 : hs1;
    int w0 = wh * 64;
    int tid = threadIdx.x;

    for (int f = tid; f < 70 * 64; f += 256) {
        int ww = f >> 6, i = f & 63;
        int wp = w0 - 3 + ww;
        xt[ww * 68 + i] = ((unsigned)wp < 128u) ? x[b * 8192 + wp * 64 + i] : 0.f;
    }
    int nw = K * 4096;
    for (int f = tid; f < nw; f += 256) {
        int j = f & 3, o = (f >> 2) & 63, i4 = (f >> 8) & 15, t = f >> 12;
        wl[f] = cw[(o * 64 + i4 * 4 + j) * K + t];
    }
    __syncthreads();

    int to = tid & 15, tw = tid >> 4;
    float acc[4][4] = {};                // [wj][oj], o = to + 16*oj, w = w0 + tw*4 + wj
    int ob = 3 - (K >> 1);
    for (int t = 0; t < K; ++t) {
        int rbase = tw * 4 + t + ob;
        for (int i4 = 0; i4 < 16; ++i4) {
            float4 a0 = *(const float4*)&xt[(rbase + 0) * 68 + i4 * 4];
            float4 a1 = *(const float4*)&xt[(rbase + 1) * 68 + i4 * 4];
            float4 a2 = *(const float4*)&xt[(rbase + 2) * 68 + i4 * 4];
            float4 a3 = *(const float4*)&xt[(rbase + 3) * 68 + i4 * 4];
            const float* wrow = &wl[(t * 16 + i4) * 256];
            float4 b0 = *(const float4*)&wrow[to * 4];
            float4 b1 = *(const float4*)&wrow[(to + 16) * 4];
            float4 b2 = *(const float4*)&wrow[(to + 32) * 4];
            float4 b3 = *(const float4*)&wrow[(to + 48) * 4];
            #define DOT4(w_, a_, b_) \
                acc[w_][0] = fmaf(a_.x, b0.x, acc[w_][0]); acc[w_][0] = fmaf(a_.y, b0.y, acc[w_][0]); \
                acc[w_][0] = fmaf(a_.z, b0.z, acc[w_][0]); acc[w_][0] = fmaf(a_.w, b0.w, acc[w_][0]); \
                acc[w_][1] = fmaf(a_.x, b1.x, acc[w_][1]); acc[w_][1] = fmaf(a_.y, b1.y, acc[w_][1]); \
                acc[w_][1] = fmaf(a_.z, b1.z, acc[w_][1]); acc[w_][1] = fmaf(a_.w, b1.w, acc[w_][1]); \
                acc[w_][2] = fmaf(a_.x, b2.x, acc[w_][2]); acc[w_][2] = fmaf(a_.y, b2.y, acc[w_][2]); \
                acc[w_][2] = fmaf(a_.z, b2.z, acc[w_][2]); acc[w_][2] = fmaf(a_.w, b2.w, acc[w_][2]); \
                acc[w_][3] = fmaf(a_.x, b3.x, acc[w_][3]); acc[w_][3] = fmaf(a_.y, b3.y, acc[w_][3]); \
                acc[w_][3] = fmaf(a_.z, b3.z, acc[w_][3]); acc[w_][3] = fmaf(a_.w, b3.w, acc[w_][3]);
            DOT4(0, a0, b)
            DOT4(1, a1, b)
            DOT4(2, a2, b)
            DOT4(3, a3, b)
            #undef DOT4
        }
    }
    #pragma unroll
    for (int wj = 0; wj < 4; ++wj) {
        int w = w0 + tw * 4 + wj;
        #pragma unroll
        for (int oj = 0; oj < 4; ++oj) {
            int o = to + 16 * oj;
            dst[b * 8192 + w * 64 + o] = fmaxf(acc[wj][oj] + cb[o], 0.f);
        }
    }
}

// ---------------- one STGAT layer (all 3 branches), in-place residual ----------------
__global__ __launch_bounds__(256) void k_stgat(
    float* __restrict__ hs0, float* __restrict__ hs1, float* __restrict__ hs2,
    const float* __restrict__ gat_w, const float* __restrict__ gat_asrc,
    const float* __restrict__ gat_adst, const float* __restrict__ gat_b,
    const float* __restrict__ gcn_w, const float* __restrict__ gcn_b, int l) {
    extern __shared__ float S[];
    const int XPo = 0;               // xp [64][132]
    const int GWo = 8448;            // phase1: gw [128][132]
    const int FTo = 8448;            // phase2+: fT [128][68]
    const int ACo = 8448 + 8704;     // A [64][68], later cw [64][68]
    const int HRo = 25344;           // h [64][132], later hg [128][66]
    const int So = 33792;
    const int Do = 33856;

    int b = blockIdx.x, br = blockIdx.y, tid = threadIdx.x;
    float* hs = (br == 0 ? hs0 : (br == 1 ? hs1 : hs2)) + b * 8192;
    int wsel = br * 2 + l;
    const float* gw = gat_w + wsel * 16384;
    const float* asr = gat_asrc + wsel * 128;
    const float* ads = gat_adst + wsel * 128;
    const float* gb = gat_b + wsel * 128;
    const float* cwp = gcn_w + wsel * 4096;
    const float* cbp = gcn_b + wsel * 64;

    for (int f = tid; f < 8192; f += 256) {
        int w = f >> 6, n = f & 63;
        S[XPo + n * 132 + w] = hs[f];
    }
    for (int f = tid; f < 16384; f += 256) {
        int wo = f >> 7, k = f & 127;
        S[GWo + wo * 132 + k] = gw[f];
    }
    __syncthreads();

    int lane = tid & 63, wq = tid >> 6;
    {
        float acc[32];
        #pragma unroll
        for (int j = 0; j < 32; ++j) acc[j] = 0.f;
        const float* xpr = &S[XPo + lane * 132];
        const float* gwb = &S[GWo + (wq * 32) * 132];
        for (int k4 = 0; k4 < 32; ++k4) {
            float4 xv = *(const float4*)(xpr + k4 * 4);
            #pragma unroll
            for (int j = 0; j < 32; ++j) {
                float4 gv = *(const float4*)(gwb + j * 132 + k4 * 4);
                acc[j] = fmaf(xv.x, gv.x, acc[j]);
                acc[j] = fmaf(xv.y, gv.y, acc[j]);
                acc[j] = fmaf(xv.z, gv.z, acc[j]);
                acc[j] = fmaf(xv.w, gv.w, acc[j]);
            }
        }
        float* hrow = &S[HRo + lane * 132 + wq * 32];
        #pragma unroll
        for (int j = 0; j < 32; ++j) hrow[j] = acc[j];
    }
    __syncthreads();
    if (tid < 128) {
        int i = tid & 63;
        const float* av = (tid < 64) ? asr : ads;
        const float* hr = &S[HRo + i * 132];
        float acc = 0.f;
        for (int k4 = 0; k4 < 32; ++k4) {
            float4 hv = *(const float4*)(hr + k4 * 4);
            float4 aw = *(const float4*)(av + k4 * 4);
            acc = fmaf(hv.x, aw.x, acc);
            acc = fmaf(hv.y, aw.y, acc);
            acc = fmaf(hv.z, aw.z, acc);
            acc = fmaf(hv.w, aw.w, acc);
        }
        S[(tid < 64 ? So : Do) + i] = acc;
    }
    __syncthreads();
    if (tid < 64) {
        float dj = S[Do + tid];
        float mx = -1e30f;
        for (int i = 0; i < 64; ++i) {
            float e = S[So + i] + dj;
            e = (e > 0.f) ? e : 0.2f * e;
            mx = fmaxf(mx, e);
        }
        float sum = 0.f;
        float* arow = &S[ACo + tid * 68];
        for (int i = 0; i < 64; ++i) {
            float e = S[So + i] + dj;
            e = (e > 0.f) ? e : 0.2f * e;
            float ex = __expf(e - mx);
            arow[i] = ex;
            sum += ex;
        }
        float rinv = 1.f / sum;
        for (int i = 0; i < 64; ++i) arow[i] *= rinv;
    }
    __syncthreads();
    {
        float acc[32];
        #pragma unroll
        for (int j = 0; j < 32; ++j) acc[j] = 0.f;
        const float* arow = &S[ACo + lane * 68];
        for (int i = 0; i < 64; ++i) {
            float a = arow[i];
            const float* hr = &S[HRo + i * 132 + wq * 32];
            #pragma unroll
            for (int w4 = 0; w4 < 8; ++w4) {
                float4 hv = *(const float4*)(hr + w4 * 4);
                acc[w4 * 4 + 0] = fmaf(a, hv.x, acc[w4 * 4 + 0]);
                acc[w4 * 4 + 1] = fmaf(a, hv.y, acc[w4 * 4 + 1]);
                acc[w4 * 4 + 2] = fmaf(a, hv.z, acc[w4 * 4 + 2]);
                acc[w4 * 4 + 3] = fmaf(a, hv.w, acc[w4 * 4 + 3]);
            }
        }
        #pragma unroll
        for (int w4 = 0; w4 < 8; ++w4) {
            float4 gv = *(const float4*)(gb + wq * 32 + w4 * 4);
            int wbase = wq * 32 + w4 * 4;
            S[FTo + (wbase + 0) * 68 + lane] = fmaxf(acc[w4 * 4 + 0] + gv.x, 0.f);
            S[FTo + (wbase + 1) * 68 + lane] = fmaxf(acc[w4 * 4 + 1] + gv.y, 0.f);
            S[FTo + (wbase + 2) * 68 + lane] = fmaxf(acc[w4 * 4 + 2] + gv.z, 0.f);
            S[FTo + (wbase + 3) * 68 + lane] = fmaxf(acc[w4 * 4 + 3] + gv.w, 0.f);
        }
    }
    __syncthreads();
    for (int f = tid; f < 4096; f += 256) {
        int c = f >> 6, k = f & 63;
        S[ACo + c * 68 + k] = cwp[f];
    }
    __syncthreads();
    {
        float acc[32];
        #pragma unroll
        for (int j = 0; j < 32; ++j) acc[j] = 0.f;
        const float* cwr = &S[ACo + lane * 68];
        for (int k4 = 0; k4 < 16; ++k4) {
            float4 cv = *(const float4*)(cwr + k4 * 4);
            const float* ftb = &S[FTo + (wq * 32) * 68 + k4 * 4];
            #pragma unroll
            for (int w = 0; w < 32; ++w) {
                float4 fv = *(const float4*)(ftb + w * 68);
                acc[w] = fmaf(cv.x, fv.x, acc[w]);
                acc[w] = fmaf(cv.y, fv.y, acc[w]);
                acc[w] = fmaf(cv.z, fv.z, acc[w]);
                acc[w] = fmaf(cv.w, fv.w, acc[w]);
            }
        }
        #pragma unroll
        for (int w = 0; w < 32; ++w) S[HRo + (wq * 32 + w) * 66 + lane] = acc[w];
    }
    __syncthreads();
    if (tid < 64) {
        int c = tid;
        float cbv = cbp[c];
        float run = 0.f;
        for (int w = 0; w < 128; ++w) {
            float dv = rsqrtf((float)(w + 1));
            run = fmaf(dv, S[HRo + w * 66 + c], run);
            float tv = fmaf(dv, run, cbv);
            S[HRo + w * 66 + c] = fmaxf(tv, 0.f);
        }
    }
    __syncthreads();
    {
        int cc = tid & 63, rr = tid >> 6;
        for (int ai = 0; ai < 32; ++ai) {
            int a = ai * 4 + rr;
            int idx = cc * 128 + a;
            int w = idx >> 6, n = idx & 63;
            hs[a * 64 + cc] = S[HRo + w * 66 + n] + S[XPo + cc * 132 + a];
        }
    }
}

// ---------------- encoder input GEMM (dir0 full) ----------------
__global__ __launch_bounds__(256) void k_encgemm(
    const float* __restrict__ hs0, const float* __restrict__ hs1, const float* __restrict__ hs2,
    const float* __restrict__ wih, const float* __restrict__ bih, const float* __restrict__ bhh,
    float* __restrict__ gx0) {
    __shared__ __align__(16) float At[32 * 132];
    __shared__ __align__(16) float Bt[32 * 68];
    int b = blockIdx.x, ny = blockIdx.y, tid = threadIdx.x;
    int g0 = ny * 64;
    int ty = tid >> 4, tx = tid & 15;
    float acc[8][4];
    #pragma unroll
    for (int r = 0; r < 8; ++r)
        #pragma unroll
        for (int c = 0; c < 4; ++c) acc[r][c] = 0.f;
    const float* hsb[3] = {hs0 + b * 8192, hs1 + b * 8192, hs2 + b * 8192};
    for (int kc = 0; kc < 6; ++kc) {
        const float* src = hsb[kc >> 1] + (kc & 1) * 32;
        for (int f = tid; f < 4096; f += 256) {
            int t = f >> 5, kk = f & 31;
            At[kk * 132 + t] = src[t * 64 + kk];
        }
        for (int f = tid; f < 2048; f += 256) {
            int gg = f >> 5, kk = f & 31;
            int g = g0 + gg;
            Bt[kk * 68 + gg] = (g < 600) ? wih[g * 192 + kc * 32 + kk] : 0.f;
        }
        __syncthreads();
        #pragma unroll 8
        for (int kk = 0; kk < 32; ++kk) {
            float a[8], bb[4];
            *(float4*)&a[0] = *(const float4*)&At[kk * 132 + ty * 8];
            *(float4*)&a[4] = *(const float4*)&At[kk * 132 + ty * 8 + 4];
            *(float4*)&bb[0] = *(const float4*)&Bt[kk * 68 + tx * 4];
            #pragma unroll
            for (int r = 0; r < 8; ++r)
                #pragma unroll
                for (int c = 0; c < 4; ++c) acc[r][c] = fmaf(a[r], bb[c], acc[r][c]);
        }
        __syncthreads();
    }
    for (int r = 0; r < 8; ++r) {
        int t = ty * 8 + r;
        for (int c = 0; c < 4; ++c) {
            int g = g0 + tx * 4 + c;
            if (g < 600) gx0[(b * 128 + t) * 600 + g] = acc[r][c] + bih[g] + bhh[g];
        }
    }
}

// ---------------- encoder dir1 gates at t=127 only ----------------
__global__ void k_encgx1(const float* __restrict__ hs0, const float* __restrict__ hs1,
                         const float* __restrict__ hs2, const float* __restrict__ wih,
                         const float* __restrict__ bih, const float* __restrict__ bhh,
                         float* __restrict__ gx1) {
    __shared__ __align__(16) float sh[192];
    int b = blockIdx.x, tid = threadIdx.x;
    if (tid < 192) {
        const float* src = (tid < 64 ? hs0 : (tid < 128 ? hs1 : hs2));
        sh[tid] = src[b * 8192 + 127 * 64 + (tid & 63)];
    }
    __syncthreads();
    const float* w1 = wih + 600 * 192;
    for (int g = tid; g < 600; g += 256) {
        float acc = bih[600 + g] + bhh[600 + g];
        const float4* wr = (const float4*)(w1 + g * 192);
        #pragma unroll 8
        for (int q = 0; q < 48; ++q) {
            float4 wv = wr[q];
            float4 hv = *(const float4*)&sh[q * 4];
            acc = fmaf(wv.x, hv.x, acc);
            acc = fmaf(wv.y, hv.y, acc);
            acc = fmaf(wv.z, hv.z, acc);
            acc = fmaf(wv.w, hv.w, acc);
        }
        gx1[b * 600 + g] = acc;
    }
}

// ---------------- prefix sums of dec_wih rows: PT[k][dg], k=0..300 ----------------
__global__ void k_ptpref(const float* __restrict__ dwih, float* __restrict__ PT) {
    int dg = blockIdx.x * 256 + threadIdx.x;
    if (dg >= 1200) return;
    const float* wr = dwih + dg * 300;
    float run = 0.f;
    PT[dg] = 0.f;
    for (int k = 0; k < 300; ++k) {
        run += wr[k];
        PT[(k + 1) * 1200 + dg] = run;
    }
}

// ---------------- PD[(dirt*600+g)*4 + seg] = segment weights for decoder x-part ----------------
__global__ void k_pd(const float* __restrict__ PT, float* __restrict__ PD) {
    int id = blockIdx.x * 256 + threadIdx.x;
    if (id >= 153600) return;                 // 2*128*600
    int g = id % 600;
    int tt = id / 600;
    int t = tt & 127, dir = tt >> 7;
    int dg = dir * 600 + g;
    int base = t * 300;
    int j0 = base >> 7;
    int ke1 = (j0 + 1) * 128 - base;
    int ke2 = ke1 + 128; ke2 = ke2 > 300 ? 300 : ke2;
    int ke3 = ke1 + 256; ke3 = ke3 > 300 ? 300 : ke3;
    float p1 = PT[ke1 * 1200 + dg];
    float p2 = PT[ke2 * 1200 + dg];
    float p3 = PT[ke3 * 1200 + dg];
    float p4 = PT[300 * 1200 + dg];
    float4 o = {p1, p2 - p1, p3 - p2, p4 - p3};
    *(float4*)&PD[id * 4] = o;
}

// ---------------- encoder LSTM: thread owns hid unit j, 4 gates in-register ----------------
// grid 256 (0..127 fwd full scan, 128..255 single bwd step), block 192
__global__ __launch_bounds__(192, 1) void k_enclstm(
    const float* __restrict__ gx0, const float* __restrict__ gx1,
    const float* __restrict__ whh, float* __restrict__ h_end) {
    int bid = blockIdx.x, j = threadIdx.x;
    if (bid >= 128) {  // one bwd step from zero state on x_{127}
        int b = bid - 128;
        if (j < 150) {
            float ai = gx1[b * 600 + j];
            float af = gx1[b * 600 + 150 + j];
            float ag = gx1[b * 600 + 300 + j];
            float ao = gx1[b * 600 + 450 + j];
            float c = sigm(ai) * tanhfast(ag);
            h_end[b * 300 + 150 + j] = sigm(ao) * tanhfast(c);
        }
        return;
    }
    __shared__ __align__(16) _Float16 shh[2][152];
    int b = bid;
    bool on = j < 150;
    v2h wv0[76], wv1[76], wv2[76], wv3[76];
    if (on) {
        const float* r0 = whh + (0 * 150 + j) * 150;
        const float* r1 = whh + (1 * 150 + j) * 150;
        const float* r2 = whh + (2 * 150 + j) * 150;
        const float* r3 = whh + (3 * 150 + j) * 150;
        #pragma unroll
        for (int p = 0; p < 75; ++p) {
            wv0[p] = pk2(r0[2 * p], r0[2 * p + 1]);
            wv1[p] = pk2(r1[2 * p], r1[2 * p + 1]);
            wv2[p] = pk2(r2[2 * p], r2[2 * p + 1]);
            wv3[p] = pk2(r3[2 * p], r3[2 * p + 1]);
        }
        wv0[75] = pk2(0.f, 0.f); wv1[75] = pk2(0.f, 0.f);
        wv2[75] = pk2(0.f, 0.f); wv3[75] = pk2(0.f, 0.f);
    }
    for (int i = j; i < 304; i += 192) ((_Float16*)shh)[i] = (_Float16)0.f;
    float c = 0.f;
    float x0 = 0.f, x1 = 0.f, x2 = 0.f, x3 = 0.f;
    if (on) {
        const float* gp = gx0 + (b * 128) * 600;
        x0 = gp[j]; x1 = gp[150 + j]; x2 = gp[300 + j]; x3 = gp[450 + j];
    }
    __syncthreads();
    for (int t = 0; t < 128; ++t) {
        float n0 = 0.f, n1 = 0.f, n2 = 0.f, n3 = 0.f;
        if (on && t < 127) {
            const float* gp = gx0 + (b * 128 + t + 1) * 600;
            n0 = gp[j]; n1 = gp[150 + j]; n2 = gp[300 + j]; n3 = gp[450 + j];
        }
        if (on) {
            const float4* hp = (const float4*)shh[t & 1];
            float a0 = x0, a1 = x1, a2 = x2, a3 = x3;
            #pragma unroll
            for (int cc = 0; cc < 19; ++cc) {
                float4 hv = hp[cc];
                v2h h0 = __builtin_bit_cast(v2h, hv.x);
                v2h h1 = __builtin_bit_cast(v2h, hv.y);
                v2h h2 = __builtin_bit_cast(v2h, hv.z);
                v2h h3 = __builtin_bit_cast(v2h, hv.w);
                a0 = fdot2(wv0[cc * 4 + 0], h0, a0); a0 = fdot2(wv0[cc * 4 + 1], h1, a0);
                a0 = fdot2(wv0[cc * 4 + 2], h2, a0); a0 = fdot2(wv0[cc * 4 + 3], h3, a0);
                a1 = fdot2(wv1[cc * 4 + 0], h0, a1); a1 = fdot2(wv1[cc * 4 + 1], h1, a1);
                a1 = fdot2(wv1[cc * 4 + 2], h2, a1); a1 = fdot2(wv1[cc * 4 + 3], h3, a1);
                a2 = fdot2(wv2[cc * 4 + 0], h0, a2); a2 = fdot2(wv2[cc * 4 + 1], h1, a2);
                a2 = fdot2(wv2[cc * 4 + 2], h2, a2); a2 = fdot2(wv2[cc * 4 + 3], h3, a2);
                a3 = fdot2(wv3[cc * 4 + 0], h0, a3); a3 = fdot2(wv3[cc * 4 + 1], h1, a3);
                a3 = fdot2(wv3[cc * 4 + 2], h2, a3); a3 = fdot2(wv3[cc * 4 + 3], h3, a3);
            }
            c = fmaf(sigm(a1), c, sigm(a0) * tanhfast(a2));
            float h = sigm(a3) * tanhfast(c);
            shh[(t + 1) & 1][j] = (_Float16)h;
            if (t == 127) h_end[b * 300 + j] = h;
        }
        x0 = n0; x1 = n1; x2 = n2; x3 = n3;
        __syncthreads();
    }
}

// ---------------- decoder LSTM (both dirs), x-part via PD table ----------------
// grid 256 (dir = bid>>7, b = bid&127), block 192
__global__ __launch_bounds__(192, 1) void k_declstm(
    const float* __restrict__ PD, const float* __restrict__ hend,
    const float* __restrict__ whh_all, const float* __restrict__ bih,
    const float* __restrict__ bhh, float* __restrict__ dec_out) {
    __shared__ __align__(16) float she[304];
    __shared__ __align__(16) _Float16 shh[2][152];
    int dir = blockIdx.x >> 7, b = blockIdx.x & 127;
    int j = threadIdx.x;
    bool on = j < 150;
    v2h wv0[76], wv1[76], wv2[76], wv3[76];
    float bias0 = 0.f, bias1 = 0.f, bias2 = 0.f, bias3 = 0.f;
    if (on) {
        const float* wb = whh_all + dir * 90000;
        const float* r0 = wb + (0 * 150 + j) * 150;
        const float* r1 = wb + (1 * 150 + j) * 150;
        const float* r2 = wb + (2 * 150 + j) * 150;
        const float* r3 = wb + (3 * 150 + j) * 150;
        #pragma unroll
        for (int p = 0; p < 75; ++p) {
            wv0[p] = pk2(r0[2 * p], r0[2 * p + 1]);
            wv1[p] = pk2(r1[2 * p], r1[2 * p + 1]);
            wv2[p] = pk2(r2[2 * p], r2[2 * p + 1]);
            wv3[p] = pk2(r3[2 * p], r3[2 * p + 1]);
        }
        wv0[75] = pk2(0.f, 0.f); wv1[75] = pk2(0.f, 0.f);
        wv2[75] = pk2(0.f, 0.f); wv3[75] = pk2(0.f, 0.f);
        int d6 = dir * 600;
        bias0 = bih[d6 + j] + bhh[d6 + j];
        bias1 = bih[d6 + 150 + j] + bhh[d6 + 150 + j];
        bias2 = bih[d6 + 300 + j] + bhh[d6 + 300 + j];
        bias3 = bih[d6 + 450 + j] + bhh[d6 + 450 + j];
    }
    for (int i = j; i < 304; i += 192) she[i] = (i < 300) ? hend[b * 300 + i] : 0.f;
    for (int i = j; i < 304; i += 192) ((_Float16*)shh)[i] = (_Float16)0.f;
    float c = 0.f;
    __syncthreads();
    for (int s = 0; s < 128; ++s) {
        int t = dir ? (127 - s) : s;
        if (on) {
            int base = t * 300;
            int j0 = base >> 7;
            const float4* pdp = (const float4*)(PD + ((dir * 128 + t) * 600) * 4);
            float4 pd0 = pdp[j];
            float4 pd1 = pdp[150 + j];
            float4 pd2 = pdp[300 + j];
            float4 pd3 = pdp[450 + j];
            float e0 = she[j0], e1 = she[j0 + 1], e2 = she[j0 + 2], e3 = she[j0 + 3];
            float a0 = bias0 + e0 * pd0.x + e1 * pd0.y + e2 * pd0.z + e3 * pd0.w;
            float a1 = bias1 + e0 * pd1.x + e1 * pd1.y + e2 * pd1.z + e3 * pd1.w;
            float a2 = bias2 + e0 * pd2.x + e1 * pd2.y + e2 * pd2.z + e3 * pd2.w;
            float a3 = bias3 + e0 * pd3.x + e1 * pd3.y + e2 * pd3.z + e3 * pd3.w;
            const float4* hp = (const float4*)shh[s & 1];
            #pragma unroll
            for (int cc = 0; cc < 19; ++cc) {
                float4 hv = hp[cc];
                v2h h0 = __builtin_bit_cast(v2h, hv.x);
                v2h h1 = __builtin_bit_cast(v2h, hv.y);
                v2h h2 = __builtin_bit_cast(v2h, hv.z);
                v2h h3 = __builtin_bit_cast(v2h, hv.w);
                a0 = fdot2(wv0[cc * 4 + 0], h0, a0); a0 = fdot2(wv0[cc * 4 + 1], h1, a0);
                a0 = fdot2(wv0[cc * 4 + 2], h2, a0); a0 = fdot2(wv0[cc * 4 + 3], h3, a0);
                a1 = fdot2(wv1[cc * 4 + 0], h0, a1); a1 = fdot2(wv1[cc * 4 + 1], h1, a1);
                a1 = fdot2(wv1[cc * 4 + 2], h2, a1); a1 = fdot2(wv1[cc * 4 + 3], h3, a1);
                a2 = fdot2(wv2[cc * 4 + 0], h0, a2); a2 = fdot2(wv2[cc * 4 + 1], h1, a2);
                a2 = fdot2(wv2[cc * 4 + 2], h2, a2); a2 = fdot2(wv2[cc * 4 + 3], h3, a2);
                a3 = fdot2(wv3[cc * 4 + 0], h0, a3); a3 = fdot2(wv3[cc * 4 + 1], h1, a3);
                a3 = fdot2(wv3[cc * 4 + 2], h2, a3); a3 = fdot2(wv3[cc * 4 + 3], h3, a3);
            }
            c = fmaf(sigm(a1), c, sigm(a0) * tanhfast(a2));
            float h = sigm(a3) * tanhfast(c);
            shh[(s + 1) & 1][j] = (_Float16)h;
            dec_out[(b * 128 + t) * 300 + dir * 150 + j] = h;
        }
        __syncthreads();
    }
}

// ---------------- final: out = dec @ fc_w^T + fc_b ----------------
__global__ __launch_bounds__(256) void k_fingemm(const float* __restrict__ dec,
                                                 const float* __restrict__ fw,
                                                 const float* __restrict__ fb,
                                                 float* __restrict__ out) {
    __shared__ __align__(16) float AsT[32 * 68];
    __shared__ __align__(16) float FwT[32 * 68];
    int r0 = blockIdx.x * 64, tid = threadIdx.x;
    int ty = tid >> 4, tx = tid & 15;
    float acc[4][4];
    #pragma unroll
    for (int r = 0; r < 4; ++r)
        #pragma unroll
        for (int c = 0; c < 4; ++c) acc[r][c] = 0.f;
    for (int kc = 0; kc < 10; ++kc) {
        int k0 = kc * 32;
        for (int f = tid; f < 2048; f += 256) {
            int m = f >> 5, kk = f & 31;
            int k = k0 + kk;
            AsT[kk * 68 + m] = (k < 300) ? dec[(r0 + m) * 300 + k] : 0.f;
        }
        for (int f = tid; f < 2048; f += 256) {
            int n = f >> 5, kk = f & 31;
            int k = k0 + kk;
            FwT[kk * 68 + n] = (k < 300) ? fw[n * 300 + k] : 0.f;
        }
        __syncthreads();
        #pragma unroll 8
        for (int kk = 0; kk < 32; ++kk) {
            float a[4], w[4];
            *(float4*)&a[0] = *(const float4*)&AsT[kk * 68 + ty * 4];
            *(float4*)&w[0] = *(const float4*)&FwT[kk * 68 + tx * 4];
            #pragma unroll
            for (int r = 0; r < 4; ++r)
                #pragma unroll
                for (int c = 0; c < 4; ++c) acc[r][c] = fmaf(a[r], w[c], acc[r][c]);
        }
        __syncthreads();
    }
    for (int r = 0; r < 4; ++r) {
        int m = r0 + ty * 4 + r;
        float4 o4;
        o4.x = acc[r][0] + fb[tx * 4 + 0];
        o4.y = acc[r][1] + fb[tx * 4 + 1];
        o4.z = acc[r][2] + fb[tx * 4 + 2];
        o4.w = acc[r][3] + fb[tx * 4 + 3];
        *(float4*)&out[m * 64 + tx * 4] = o4;
    }
}

// ---------------- host launcher ----------------
extern "C" void kernel_launch(void* const* d_in, const int* in_sizes, int n_in,
                              void* d_out, int out_size, void* d_ws, size_t ws_size,
                              hipStream_t stream) {
    const float* x = (const float*)d_in[0];
    const float* c2w = (const float*)d_in[3];
    const float* c2b = (const float*)d_in[4];
    const float* c3w = (const float*)d_in[5];
    const float* c3b = (const float*)d_in[6];
    const float* gatw = (const float*)d_in[7];
    const float* gatas = (const float*)d_in[8];
    const float* gatad = (const float*)d_in[9];
    const float* gatb = (const float*)d_in[10];
    const float* gcnw = (const float*)d_in[11];
    const float* gcnb = (const float*)d_in[12];
    const float* lwih = (const float*)d_in[13];
    const float* lwhh = (const float*)d_in[14];
    const float* lbih = (const float*)d_in[15];
    const float* lbhh = (const float*)d_in[16];
    const float* dwih = (const float*)d_in[17];
    const float* dwhh = (const float*)d_in[18];
    const float* dbih = (const float*)d_in[19];
    const float* dbhh = (const float*)d_in[20];
    const float* fcw = (const float*)d_in[21];
    const float* fcb = (const float*)d_in[22];
    float* out = (float*)d_out;
    float* ws = (float*)d_ws;

    float* hs0 = ws;                    // 1,048,576
    float* hs1 = ws + 1048576;          // 1,048,576
    float* hs2 = ws + 2097152;          // 1,048,576
    float* gx0 = ws + 3145728;          // 9,830,400
    float* gx1 = ws + 12976128;         // 76,800
    float* hend = ws + 13052928;        // 38,400
    float* PT = ws + 13091328;          // 361,200
    float* dec = ws + 13452528;         // 4,915,200
    float* PD = hs0;                    // 614,400 — overlays hs0 (dead after encgemm/encgx1)

    k_copy<<<1024, 256, 0, stream>>>(x, hs0);
    k_conv2<<<dim3(128, 2, 2), 256, (70 * 68 + 7 * 16 * 256) * 4, stream>>>(
        x, c2w, c2b, c3w, c3b, hs1, hs2);
    for (int l = 0; l < 2; ++l)
        k_stgat<<<dim3(128, 3), 256, 33920 * 4, stream>>>(hs0, hs1, hs2, gatw, gatas,
                                                          gatad, gatb, gcnw, gcnb, l);
    k_encgemm<<<dim3(128, 10), 256, 0, stream>>>(hs0, hs1, hs2, lwih, lbih, lbhh, gx0);
    k_encgx1<<<128, 256, 0, stream>>>(hs0, hs1, hs2, lwih, lbih, lbhh, gx1);
    k_ptpref<<<5, 256, 0, stream>>>(dwih, PT);
    k_pd<<<600, 256, 0, stream>>>(PT, PD);   // after encgemm/encgx1: hs0 region now dead
    k_enclstm<<<256, 192, 0, stream>>>(gx0, gx1, lwhh, hend);
    k_declstm<<<256, 192, 0, stream>>>(PD, hend, dwhh, dbih, dbhh, dec);
    k_fingemm<<<256, 256, 0, stream>>>(dec, fcw, fcb, out);
}

// Round 3
// 791.749 us; speedup vs baseline: 2.1189x; 1.3287x over previous
//
#include <hip/hip_runtime.h>
#include <hip/hip_fp16.h>

// ---------------- model dims ----------------
// B=128, W=128, N=64, HID=150, L=2
// gates = 4*HID = 600 ; enc input D = 3*N = 192 ; dec input = 2*HID = 300

typedef _Float16 v2h __attribute__((ext_vector_type(2)));

__device__ __forceinline__ float sigm(float x) {
    return 1.0f / (1.0f + __expf(-x));
}
__device__ __forceinline__ float tanhfast(float x) {
    return 2.0f / (1.0f + __expf(-2.0f * x)) - 1.0f;
}
__device__ __forceinline__ v2h pk2(float a, float b) {
    v2h r; r[0] = (_Float16)a; r[1] = (_Float16)b; return r;
}
__device__ __forceinline__ float fdot2(v2h a, v2h b, float c) {
#if __has_builtin(__builtin_amdgcn_fdot2)
    return __builtin_amdgcn_fdot2(a, b, c, false);
#else
    return c + (float)a[0] * (float)b[0] + (float)a[1] * (float)b[1];
#endif
}

// ---------------- copy x -> hs0 ----------------
__global__ void k_copy(const float* __restrict__ x, float* __restrict__ hs0) {
    int i = blockIdx.x * 256 + threadIdx.x;           // 262144 float4
    ((float4*)hs0)[i] = ((const float4*)x)[i];
}

// ---------------- conv branches (merged) ----------------
__global__ __launch_bounds__(256) void k_conv2(
    const float* __restrict__ x,
    const float* __restrict__ cw5, const float* __restrict__ cb5,
    const float* __restrict__ cw7, const float* __restrict__ cb7,
    float* __restrict__ hs1, float* __restrict__ hs2) {
    extern __shared__ float S[];
    float* xt = S;              // [70][68]
    float* wl = S + 70 * 68;    // [(t*16+i4)*256 + o*4 + j]
    int b = blockIdx.x, wh = blockIdx.y, br = blockIdx.z;
    int K = br ? 7 : 5;
    const float* cw = br ? cw7 : cw5;
    const float* cb = br ? cb7 : cb5;
    float* dst = br ? hs2 : hs1;
    int w0 = wh * 64;
    int tid = threadIdx.x;

    for (int f = tid; f < 70 * 64; f += 256) {
        int ww = f >> 6, i = f & 63;
        int wp = w0 - 3 + ww;
        xt[ww * 68 + i] = ((unsigned)wp < 128u) ? x[b * 8192 + wp * 64 + i] : 0.f;
    }
    int nw = K * 4096;
    for (int f = tid; f < nw; f += 256) {
        int j = f & 3, o = (f >> 2) & 63, i4 = (f >> 8) & 15, t = f >> 12;
        wl[f] = cw[(o * 64 + i4 * 4 + j) * K + t];
    }
    __syncthreads();

    int to = tid & 15, tw = tid >> 4;
    float acc[4][4] = {};
    int ob = 3 - (K >> 1);
    for (int t = 0; t < K; ++t) {
        int rbase = tw * 4 + t + ob;
        for (int i4 = 0; i4 < 16; ++i4) {
            float4 a0 = *(const float4*)&xt[(rbase + 0) * 68 + i4 * 4];
            float4 a1 = *(const float4*)&xt[(rbase + 1) * 68 + i4 * 4];
            float4 a2 = *(const float4*)&xt[(rbase + 2) * 68 + i4 * 4];
            float4 a3 = *(const float4*)&xt[(rbase + 3) * 68 + i4 * 4];
            const float* wrow = &wl[(t * 16 + i4) * 256];
            float4 b0 = *(const float4*)&wrow[to * 4];
            float4 b1 = *(const float4*)&wrow[(to + 16) * 4];
            float4 b2 = *(const float4*)&wrow[(to + 32) * 4];
            float4 b3 = *(const float4*)&wrow[(to + 48) * 4];
            #define DOT4(w_, a_) \
                acc[w_][0] = fmaf(a_.x, b0.x, acc[w_][0]); acc[w_][0] = fmaf(a_.y, b0.y, acc[w_][0]); \
                acc[w_][0] = fmaf(a_.z, b0.z, acc[w_][0]); acc[w_][0] = fmaf(a_.w, b0.w, acc[w_][0]); \
                acc[w_][1] = fmaf(a_.x, b1.x, acc[w_][1]); acc[w_][1] = fmaf(a_.y, b1.y, acc[w_][1]); \
                acc[w_][1] = fmaf(a_.z, b1.z, acc[w_][1]); acc[w_][1] = fmaf(a_.w, b1.w, acc[w_][1]); \
                acc[w_][2] = fmaf(a_.x, b2.x, acc[w_][2]); acc[w_][2] = fmaf(a_.y, b2.y, acc[w_][2]); \
                acc[w_][2] = fmaf(a_.z, b2.z, acc[w_][2]); acc[w_][2] = fmaf(a_.w, b2.w, acc[w_][2]); \
                acc[w_][3] = fmaf(a_.x, b3.x, acc[w_][3]); acc[w_][3] = fmaf(a_.y, b3.y, acc[w_][3]); \
                acc[w_][3] = fmaf(a_.z, b3.z, acc[w_][3]); acc[w_][3] = fmaf(a_.w, b3.w, acc[w_][3]);
            DOT4(0, a0)
            DOT4(1, a1)
            DOT4(2, a2)
            DOT4(3, a3)
            #undef DOT4
        }
    }
    #pragma unroll
    for (int wj = 0; wj < 4; ++wj) {
        int w = w0 + tw * 4 + wj;
        #pragma unroll
        for (int oj = 0; oj < 4; ++oj) {
            int o = to + 16 * oj;
            dst[b * 8192 + w * 64 + o] = fmaxf(acc[wj][oj] + cb[o], 0.f);
        }
    }
}

// ---------------- one STGAT layer (all 3 branches), in-place residual ----------------
__global__ __launch_bounds__(256) void k_stgat(
    float* __restrict__ hs0, float* __restrict__ hs1, float* __restrict__ hs2,
    const float* __restrict__ gat_w, const float* __restrict__ gat_asrc,
    const float* __restrict__ gat_adst, const float* __restrict__ gat_b,
    const float* __restrict__ gcn_w, const float* __restrict__ gcn_b, int l) {
    extern __shared__ float S[];
    const int XPo = 0;               // xp [64][132]
    const int GWo = 8448;            // phase1: gw [128][132]
    const int FTo = 8448;            // phase2+: fT [128][68]
    const int ACo = 8448 + 8704;     // A [64][68], later cw [64][68]
    const int HRo = 25344;           // h [64][132], later hg [128][66]
    const int So = 33792;
    const int Do = 33856;

    int b = blockIdx.x, br = blockIdx.y, tid = threadIdx.x;
    float* hs = (br == 0 ? hs0 : (br == 1 ? hs1 : hs2)) + b * 8192;
    int wsel = br * 2 + l;
    const float* gw = gat_w + wsel * 16384;
    const float* asr = gat_asrc + wsel * 128;
    const float* ads = gat_adst + wsel * 128;
    const float* gb = gat_b + wsel * 128;
    const float* cwp = gcn_w + wsel * 4096;
    const float* cbp = gcn_b + wsel * 64;

    for (int f = tid; f < 8192; f += 256) {
        int w = f >> 6, n = f & 63;
        S[XPo + n * 132 + w] = hs[f];
    }
    for (int f = tid; f < 16384; f += 256) {
        int wo = f >> 7, k = f & 127;
        S[GWo + wo * 132 + k] = gw[f];
    }
    __syncthreads();

    int lane = tid & 63, wq = tid >> 6;
    {
        float acc[32];
        #pragma unroll
        for (int j = 0; j < 32; ++j) acc[j] = 0.f;
        const float* xpr = &S[XPo + lane * 132];
        const float* gwb = &S[GWo + (wq * 32) * 132];
        for (int k4 = 0; k4 < 32; ++k4) {
            float4 xv = *(const float4*)(xpr + k4 * 4);
            #pragma unroll
            for (int j = 0; j < 32; ++j) {
                float4 gv = *(const float4*)(gwb + j * 132 + k4 * 4);
                acc[j] = fmaf(xv.x, gv.x, acc[j]);
                acc[j] = fmaf(xv.y, gv.y, acc[j]);
                acc[j] = fmaf(xv.z, gv.z, acc[j]);
                acc[j] = fmaf(xv.w, gv.w, acc[j]);
            }
        }
        float* hrow = &S[HRo + lane * 132 + wq * 32];
        #pragma unroll
        for (int j = 0; j < 32; ++j) hrow[j] = acc[j];
    }
    __syncthreads();
    if (tid < 128) {
        int i = tid & 63;
        const float* av = (tid < 64) ? asr : ads;
        const float* hr = &S[HRo + i * 132];
        float acc = 0.f;
        for (int k4 = 0; k4 < 32; ++k4) {
            float4 hv = *(const float4*)(hr + k4 * 4);
            float4 aw = *(const float4*)(av + k4 * 4);
            acc = fmaf(hv.x, aw.x, acc);
            acc = fmaf(hv.y, aw.y, acc);
            acc = fmaf(hv.z, aw.z, acc);
            acc = fmaf(hv.w, aw.w, acc);
        }
        S[(tid < 64 ? So : Do) + i] = acc;
    }
    __syncthreads();
    if (tid < 64) {
        float dj = S[Do + tid];
        float mx = -1e30f;
        for (int i = 0; i < 64; ++i) {
            float e = S[So + i] + dj;
            e = (e > 0.f) ? e : 0.2f * e;
            mx = fmaxf(mx, e);
        }
        float sum = 0.f;
        float* arow = &S[ACo + tid * 68];
        for (int i = 0; i < 64; ++i) {
            float e = S[So + i] + dj;
            e = (e > 0.f) ? e : 0.2f * e;
            float ex = __expf(e - mx);
            arow[i] = ex;
            sum += ex;
        }
        float rinv = 1.f / sum;
        for (int i = 0; i < 64; ++i) arow[i] *= rinv;
    }
    __syncthreads();
    {
        float acc[32];
        #pragma unroll
        for (int j = 0; j < 32; ++j) acc[j] = 0.f;
        const float* arow = &S[ACo + lane * 68];
        for (int i = 0; i < 64; ++i) {
            float a = arow[i];
            const float* hr = &S[HRo + i * 132 + wq * 32];
            #pragma unroll
            for (int w4 = 0; w4 < 8; ++w4) {
                float4 hv = *(const float4*)(hr + w4 * 4);
                acc[w4 * 4 + 0] = fmaf(a, hv.x, acc[w4 * 4 + 0]);
                acc[w4 * 4 + 1] = fmaf(a, hv.y, acc[w4 * 4 + 1]);
                acc[w4 * 4 + 2] = fmaf(a, hv.z, acc[w4 * 4 + 2]);
                acc[w4 * 4 + 3] = fmaf(a, hv.w, acc[w4 * 4 + 3]);
            }
        }
        #pragma unroll
        for (int w4 = 0; w4 < 8; ++w4) {
            float4 gv = *(const float4*)(gb + wq * 32 + w4 * 4);
            int wbase = wq * 32 + w4 * 4;
            S[FTo + (wbase + 0) * 68 + lane] = fmaxf(acc[w4 * 4 + 0] + gv.x, 0.f);
            S[FTo + (wbase + 1) * 68 + lane] = fmaxf(acc[w4 * 4 + 1] + gv.y, 0.f);
            S[FTo + (wbase + 2) * 68 + lane] = fmaxf(acc[w4 * 4 + 2] + gv.z, 0.f);
            S[FTo + (wbase + 3) * 68 + lane] = fmaxf(acc[w4 * 4 + 3] + gv.w, 0.f);
        }
    }
    __syncthreads();
    for (int f = tid; f < 4096; f += 256) {
        int c = f >> 6, k = f & 63;
        S[ACo + c * 68 + k] = cwp[f];
    }
    __syncthreads();
    {
        float acc[32];
        #pragma unroll
        for (int j = 0; j < 32; ++j) acc[j] = 0.f;
        const float* cwr = &S[ACo + lane * 68];
        for (int k4 = 0; k4 < 16; ++k4) {
            float4 cv = *(const float4*)(cwr + k4 * 4);
            const float* ftb = &S[FTo + (wq * 32) * 68 + k4 * 4];
            #pragma unroll
            for (int w = 0; w < 32; ++w) {
                float4 fv = *(const float4*)(ftb + w * 68);
                acc[w] = fmaf(cv.x, fv.x, acc[w]);
                acc[w] = fmaf(cv.y, fv.y, acc[w]);
                acc[w] = fmaf(cv.z, fv.z, acc[w]);
                acc[w] = fmaf(cv.w, fv.w, acc[w]);
            }
        }
        #pragma unroll
        for (int w = 0; w < 32; ++w) S[HRo + (wq * 32 + w) * 66 + lane] = acc[w];
    }
    __syncthreads();
    if (tid < 64) {
        int c = tid;
        float cbv = cbp[c];
        float run = 0.f;
        for (int w = 0; w < 128; ++w) {
            float dv = rsqrtf((float)(w + 1));
            run = fmaf(dv, S[HRo + w * 66 + c], run);
            float tv = fmaf(dv, run, cbv);
            S[HRo + w * 66 + c] = fmaxf(tv, 0.f);
        }
    }
    __syncthreads();
    {
        int cc = tid & 63, rr = tid >> 6;
        for (int ai = 0; ai < 32; ++ai) {
            int a = ai * 4 + rr;
            int idx = cc * 128 + a;
            int w = idx >> 6, n = idx & 63;
            hs[a * 64 + cc] = S[HRo + w * 66 + n] + S[XPo + cc * 132 + a];
        }
    }
}

// ---------------- encoder input GEMM (dir0 full) ----------------
__global__ __launch_bounds__(256) void k_encgemm(
    const float* __restrict__ hs0, const float* __restrict__ hs1, const float* __restrict__ hs2,
    const float* __restrict__ wih, const float* __restrict__ bih, const float* __restrict__ bhh,
    float* __restrict__ gx0) {
    __shared__ __align__(16) float At[32 * 132];
    __shared__ __align__(16) float Bt[32 * 68];
    int b = blockIdx.x, ny = blockIdx.y, tid = threadIdx.x;
    int g0 = ny * 64;
    int ty = tid >> 4, tx = tid & 15;
    float acc[8][4];
    #pragma unroll
    for (int r = 0; r < 8; ++r)
        #pragma unroll
        for (int c = 0; c < 4; ++c) acc[r][c] = 0.f;
    const float* hsb[3] = {hs0 + b * 8192, hs1 + b * 8192, hs2 + b * 8192};
    for (int kc = 0; kc < 6; ++kc) {
        const float* src = hsb[kc >> 1] + (kc & 1) * 32;
        for (int f = tid; f < 4096; f += 256) {
            int t = f >> 5, kk = f & 31;
            At[kk * 132 + t] = src[t * 64 + kk];
        }
        for (int f = tid; f < 2048; f += 256) {
            int gg = f >> 5, kk = f & 31;
            int g = g0 + gg;
            Bt[kk * 68 + gg] = (g < 600) ? wih[g * 192 + kc * 32 + kk] : 0.f;
        }
        __syncthreads();
        #pragma unroll 8
        for (int kk = 0; kk < 32; ++kk) {
            float a[8], bb[4];
            *(float4*)&a[0] = *(const float4*)&At[kk * 132 + ty * 8];
            *(float4*)&a[4] = *(const float4*)&At[kk * 132 + ty * 8 + 4];
            *(float4*)&bb[0] = *(const float4*)&Bt[kk * 68 + tx * 4];
            #pragma unroll
            for (int r = 0; r < 8; ++r)
                #pragma unroll
                for (int c = 0; c < 4; ++c) acc[r][c] = fmaf(a[r], bb[c], acc[r][c]);
        }
        __syncthreads();
    }
    for (int r = 0; r < 8; ++r) {
        int t = ty * 8 + r;
        for (int c = 0; c < 4; ++c) {
            int g = g0 + tx * 4 + c;
            if (g < 600) gx0[(b * 128 + t) * 600 + g] = acc[r][c] + bih[g] + bhh[g];
        }
    }
}

// ---------------- encoder dir1 gates at t=127 only ----------------
__global__ void k_encgx1(const float* __restrict__ hs0, const float* __restrict__ hs1,
                         const float* __restrict__ hs2, const float* __restrict__ wih,
                         const float* __restrict__ bih, const float* __restrict__ bhh,
                         float* __restrict__ gx1) {
    __shared__ __align__(16) float sh[192];
    int b = blockIdx.x, tid = threadIdx.x;
    if (tid < 192) {
        const float* src = (tid < 64 ? hs0 : (tid < 128 ? hs1 : hs2));
        sh[tid] = src[b * 8192 + 127 * 64 + (tid & 63)];
    }
    __syncthreads();
    const float* w1 = wih + 600 * 192;
    for (int g = tid; g < 600; g += 256) {
        float acc = bih[600 + g] + bhh[600 + g];
        const float4* wr = (const float4*)(w1 + g * 192);
        #pragma unroll 8
        for (int q = 0; q < 48; ++q) {
            float4 wv = wr[q];
            float4 hv = *(const float4*)&sh[q * 4];
            acc = fmaf(wv.x, hv.x, acc);
            acc = fmaf(wv.y, hv.y, acc);
            acc = fmaf(wv.z, hv.z, acc);
            acc = fmaf(wv.w, hv.w, acc);
        }
        gx1[b * 600 + g] = acc;
    }
}

// ---------------- prefix sums of dec_wih rows: PT[k][dg], k=0..300 ----------------
__global__ void k_ptpref(const float* __restrict__ dwih, float* __restrict__ PT) {
    int dg = blockIdx.x * 256 + threadIdx.x;
    if (dg >= 1200) return;
    const float* wr = dwih + dg * 300;
    float run = 0.f;
    PT[dg] = 0.f;
    for (int k = 0; k < 300; ++k) {
        run += wr[k];
        PT[(k + 1) * 1200 + dg] = run;
    }
}

// ---------------- PD[(dirt*600+g)*4 + seg] ----------------
__global__ void k_pd(const float* __restrict__ PT, float* __restrict__ PD) {
    int id = blockIdx.x * 256 + threadIdx.x;
    if (id >= 153600) return;                 // 2*128*600
    int g = id % 600;
    int tt = id / 600;
    int t = tt & 127, dir = tt >> 7;
    int dg = dir * 600 + g;
    int base = t * 300;
    int j0 = base >> 7;
    int ke1 = (j0 + 1) * 128 - base;
    int ke2 = ke1 + 128; ke2 = ke2 > 300 ? 300 : ke2;
    int ke3 = ke1 + 256; ke3 = ke3 > 300 ? 300 : ke3;
    float p1 = PT[ke1 * 1200 + dg];
    float p2 = PT[ke2 * 1200 + dg];
    float p3 = PT[ke3 * 1200 + dg];
    float p4 = PT[300 * 1200 + dg];
    float4 o = {p1, p2 - p1, p3 - p2, p4 - p3};
    *(float4*)&PD[id * 4] = o;
}

// ---------------- encoder LSTM: thread = one gate row; quad = one hidden unit ----------------
// grid 256 (0..127 fwd full scan, 128..255 single bwd step), block 640 (600 active)
__global__ __launch_bounds__(640, 3) void k_enclstm(
    const float* __restrict__ gx0, const float* __restrict__ gx1,
    const float* __restrict__ whh, float* __restrict__ h_end) {
    int bid = blockIdx.x, t = threadIdx.x;
    if (bid >= 128) {  // one bwd step from zero state on x_{127}
        int b = bid - 128;
        if (t < 150) {
            float ai = gx1[b * 600 + t];
            float ag = gx1[b * 600 + 300 + t];
            float ao = gx1[b * 600 + 450 + t];
            float c = sigm(ai) * tanhfast(ag);
            h_end[b * 300 + 150 + t] = sigm(ao) * tanhfast(c);
        }
        return;
    }
    __shared__ __align__(16) _Float16 hbuf[2][152];
    int b = bid;
    bool on = t < 600;
    int j = t >> 2, g4 = t & 3;
    int grow = g4 * 150 + j;          // raw gate row (i,f,g,o blocks of 150)
    v2h wv[76];
    #pragma unroll
    for (int p = 0; p < 76; ++p) wv[p] = pk2(0.f, 0.f);
    if (on) {
        const float* r = whh + grow * 150;
        #pragma unroll
        for (int p = 0; p < 75; ++p) wv[p] = pk2(r[2 * p], r[2 * p + 1]);
    }
    for (int i = t; i < 304; i += 640) ((_Float16*)hbuf)[i] = (_Float16)0.f;
    float c = 0.f;
    float xc = on ? gx0[(b * 128) * 600 + grow] : 0.f;
    __syncthreads();
    for (int s = 0; s < 128; ++s) {
        float xn = (on && s < 127) ? gx0[(b * 128 + s + 1) * 600 + grow] : 0.f;
        float s0 = 0.f, s1 = 0.f, s2 = 0.f, s3 = 0.f;
        const float4* hp = (const float4*)hbuf[s & 1];
        #pragma unroll
        for (int cc = 0; cc < 19; ++cc) {
            float4 hv = hp[cc];
            s0 = fdot2(wv[4 * cc + 0], __builtin_bit_cast(v2h, hv.x), s0);
            s1 = fdot2(wv[4 * cc + 1], __builtin_bit_cast(v2h, hv.y), s1);
            s2 = fdot2(wv[4 * cc + 2], __builtin_bit_cast(v2h, hv.z), s2);
            s3 = fdot2(wv[4 * cc + 3], __builtin_bit_cast(v2h, hv.w), s3);
        }
        float a = xc + ((s0 + s1) + (s2 + s3));
        bool isg = (g4 == 2);
        float sg = sigm(isg ? 2.f * a : a);
        float act = isg ? fmaf(2.f, sg, -1.f) : sg;   // tanh(x)=2*sigm(2x)-1
        float vf = __shfl_xor(act, 1);
        float vg = __shfl_xor(act, 2);
        float vo = __shfl_xor(vf, 2);
        if (on && g4 == 0) {
            c = fmaf(vf, c, act * vg);                // c = sigm(f)*c + sigm(i)*tanh(g)
            float h = vo * tanhfast(c);               // h = sigm(o)*tanh(c)
            hbuf[(s + 1) & 1][j] = (_Float16)h;
            if (s == 127) h_end[b * 300 + j] = h;
        }
        xc = xn;
        __syncthreads();
    }
}

// ---------------- decoder LSTM (both dirs), x-part via PD table ----------------
// grid 256 (dir = bid>>7, b = bid&127), block 640 (600 active)
__global__ __launch_bounds__(640, 3) void k_declstm(
    const float* __restrict__ PD, const float* __restrict__ hend,
    const float* __restrict__ whh_all, const float* __restrict__ bih,
    const float* __restrict__ bhh, float* __restrict__ dec_out) {
    __shared__ __align__(16) float she[304];
    __shared__ __align__(16) _Float16 hbuf[2][152];
    int dir = blockIdx.x >> 7, b = blockIdx.x & 127;
    int t = threadIdx.x;
    bool on = t < 600;
    int j = t >> 2, g4 = t & 3;
    int grow = g4 * 150 + j;
    v2h wv[76];
    #pragma unroll
    for (int p = 0; p < 76; ++p) wv[p] = pk2(0.f, 0.f);
    float bias = 0.f;
    if (on) {
        const float* r = whh_all + dir * 90000 + grow * 150;
        #pragma unroll
        for (int p = 0; p < 75; ++p) wv[p] = pk2(r[2 * p], r[2 * p + 1]);
        bias = bih[dir * 600 + grow] + bhh[dir * 600 + grow];
    }
    for (int i = t; i < 304; i += 640) she[i] = (i < 300) ? hend[b * 300 + i] : 0.f;
    for (int i = t; i < 304; i += 640) ((_Float16*)hbuf)[i] = (_Float16)0.f;
    float c = 0.f;
    int t0 = dir ? 127 : 0;
    float4 pd = {0.f, 0.f, 0.f, 0.f};
    if (on) pd = *(const float4*)&PD[((dir * 128 + t0) * 600 + grow) * 4];
    __syncthreads();
    for (int s = 0; s < 128; ++s) {
        int tt = dir ? (127 - s) : s;
        float4 pdn = {0.f, 0.f, 0.f, 0.f};
        if (on && s < 127) {
            int tn = dir ? (126 - s) : (s + 1);
            pdn = *(const float4*)&PD[((dir * 128 + tn) * 600 + grow) * 4];
        }
        int j0 = (tt * 300) >> 7;
        float e0 = she[j0], e1 = she[j0 + 1], e2 = she[j0 + 2], e3 = she[j0 + 3];
        float a = bias + e0 * pd.x + e1 * pd.y + e2 * pd.z + e3 * pd.w;
        float s0 = 0.f, s1 = 0.f, s2 = 0.f, s3 = 0.f;
        const float4* hp = (const float4*)hbuf[s & 1];
        #pragma unroll
        for (int cc = 0; cc < 19; ++cc) {
            float4 hv = hp[cc];
            s0 = fdot2(wv[4 * cc + 0], __builtin_bit_cast(v2h, hv.x), s0);
            s1 = fdot2(wv[4 * cc + 1], __builtin_bit_cast(v2h, hv.y), s1);
            s2 = fdot2(wv[4 * cc + 2], __builtin_bit_cast(v2h, hv.z), s2);
            s3 = fdot2(wv[4 * cc + 3], __builtin_bit_cast(v2h, hv.w), s3);
        }
        a += (s0 + s1) + (s2 + s3);
        bool isg = (g4 == 2);
        float sg = sigm(isg ? 2.f * a : a);
        float act = isg ? fmaf(2.f, sg, -1.f) : sg;
        float vf = __shfl_xor(act, 1);
        float vg = __shfl_xor(act, 2);
        float vo = __shfl_xor(vf, 2);
        if (on && g4 == 0) {
            c = fmaf(vf, c, act * vg);
            float h = vo * tanhfast(c);
            hbuf[(s + 1) & 1][j] = (_Float16)h;
            dec_out[(b * 128 + tt) * 300 + dir * 150 + j] = h;
        }
        pd = pdn;
        __syncthreads();
    }
}

// ---------------- final: out = dec @ fc_w^T + fc_b ----------------
__global__ __launch_bounds__(256) void k_fingemm(const float* __restrict__ dec,
                                                 const float* __restrict__ fw,
                                                 const float* __restrict__ fb,
                                                 float* __restrict__ out) {
    __shared__ __align__(16) float AsT[32 * 68];
    __shared__ __align__(16) float FwT[32 * 68];
    int r0 = blockIdx.x * 64, tid = threadIdx.x;
    int ty = tid >> 4, tx = tid & 15;
    float acc[4][4];
    #pragma unroll
    for (int r = 0; r < 4; ++r)
        #pragma unroll
        for (int c = 0; c < 4; ++c) acc[r][c] = 0.f;
    for (int kc = 0; kc < 10; ++kc) {
        int k0 = kc * 32;
        for (int f = tid; f < 2048; f += 256) {
            int m = f >> 5, kk = f & 31;
            int k = k0 + kk;
            AsT[kk * 68 + m] = (k < 300) ? dec[(r0 + m) * 300 + k] : 0.f;
        }
        for (int f = tid; f < 2048; f += 256) {
            int n = f >> 5, kk = f & 31;
            int k = k0 + kk;
            FwT[kk * 68 + n] = (k < 300) ? fw[n * 300 + k] : 0.f;
        }
        __syncthreads();
        #pragma unroll 8
        for (int kk = 0; kk < 32; ++kk) {
            float a[4], w[4];
            *(float4*)&a[0] = *(const float4*)&AsT[kk * 68 + ty * 4];
            *(float4*)&w[0] = *(const float4*)&FwT[kk * 68 + tx * 4];
            #pragma unroll
            for (int r = 0; r < 4; ++r)
                #pragma unroll
                for (int c = 0; c < 4; ++c) acc[r][c] = fmaf(a[r], w[c], acc[r][c]);
        }
        __syncthreads();
    }
    for (int r = 0; r < 4; ++r) {
        int m = r0 + ty * 4 + r;
        float4 o4;
        o4.x = acc[r][0] + fb[tx * 4 + 0];
        o4.y = acc[r][1] + fb[tx * 4 + 1];
        o4.z = acc[r][2] + fb[tx * 4 + 2];
        o4.w = acc[r][3] + fb[tx * 4 + 3];
        *(float4*)&out[m * 64 + tx * 4] = o4;
    }
}

// ---------------- host launcher ----------------
extern "C" void kernel_launch(void* const* d_in, const int* in_sizes, int n_in,
                              void* d_out, int out_size, void* d_ws, size_t ws_size,
                              hipStream_t stream) {
    const float* x = (const float*)d_in[0];
    const float* c2w = (const float*)d_in[3];
    const float* c2b = (const float*)d_in[4];
    const float* c3w = (const float*)d_in[5];
    const float* c3b = (const float*)d_in[6];
    const float* gatw = (const float*)d_in[7];
    const float* gatas = (const float*)d_in[8];
    const float* gatad = (const float*)d_in[9];
    const float* gatb = (const float*)d_in[10];
    const float* gcnw = (const float*)d_in[11];
    const float* gcnb = (const float*)d_in[12];
    const float* lwih = (const float*)d_in[13];
    const float* lwhh = (const float*)d_in[14];
    const float* lbih = (const float*)d_in[15];
    const float* lbhh = (const float*)d_in[16];
    const float* dwih = (const float*)d_in[17];
    const float* dwhh = (const float*)d_in[18];
    const float* dbih = (const float*)d_in[19];
    const float* dbhh = (const float*)d_in[20];
    const float* fcw = (const float*)d_in[21];
    const float* fcb = (const float*)d_in[22];
    float* out = (float*)d_out;
    float* ws = (float*)d_ws;

    float* hs0 = ws;                    // 1,048,576
    float* hs1 = ws + 1048576;          // 1,048,576
    float* hs2 = ws + 2097152;          // 1,048,576
    float* gx0 = ws + 3145728;          // 9,830,400
    float* gx1 = ws + 12976128;         // 76,800
    float* hend = ws + 13052928;        // 38,400
    float* PT = ws + 13091328;          // 361,200
    float* dec = ws + 13452528;         // 4,915,200
    float* PD = hs0;                    // 614,400 — overlays hs0 (dead after encgemm/encgx1)

    k_copy<<<1024, 256, 0, stream>>>(x, hs0);
    k_conv2<<<dim3(128, 2, 2), 256, (70 * 68 + 7 * 16 * 256) * 4, stream>>>(
        x, c2w, c2b, c3w, c3b, hs1, hs2);
    for (int l = 0; l < 2; ++l)
        k_stgat<<<dim3(128, 3), 256, 33920 * 4, stream>>>(hs0, hs1, hs2, gatw, gatas,
                                                          gatad, gatb, gcnw, gcnb, l);
    k_encgemm<<<dim3(128, 10), 256, 0, stream>>>(hs0, hs1, hs2, lwih, lbih, lbhh, gx0);
    k_encgx1<<<128, 256, 0, stream>>>(hs0, hs1, hs2, lwih, lbih, lbhh, gx1);
    k_ptpref<<<5, 256, 0, stream>>>(dwih, PT);
    k_pd<<<600, 256, 0, stream>>>(PT, PD);   // after encgemm/encgx1: hs0 region now dead
    k_enclstm<<<256, 640, 0, stream>>>(gx0, gx1, lwhh, hend);
    k_declstm<<<256, 640, 0, stream>>>(PD, hend, dwhh, dbih, dbhh, dec);
    k_fingemm<<<256, 256, 0, stream>>>(dec, fcw, fcb, out);
}

// Round 4
// 564.994 us; speedup vs baseline: 2.9692x; 1.4013x over previous
//
#include <hip/hip_runtime.h>
#include <hip/hip_fp16.h>

// ---------------- model dims ----------------
// B=128, W=128, N=64, HID=150, L=2
// gates = 4*HID = 600 ; enc input D = 3*N = 192 ; dec input = 2*HID = 300

typedef _Float16 v2h __attribute__((ext_vector_type(2)));

__device__ __forceinline__ float sigm(float x) {
    return 1.0f / (1.0f + __expf(-x));
}
__device__ __forceinline__ float tanhfast(float x) {
    return 2.0f / (1.0f + __expf(-2.0f * x)) - 1.0f;
}
__device__ __forceinline__ v2h pk2(float a, float b) {
    v2h r; r[0] = (_Float16)a; r[1] = (_Float16)b; return r;
}
__device__ __forceinline__ unsigned pku(float a, float b) {
    return __builtin_bit_cast(unsigned, pk2(a, b));
}
__device__ __forceinline__ v2h upk(unsigned u) { return __builtin_bit_cast(v2h, u); }
__device__ __forceinline__ float fdot2(v2h a, v2h b, float c) {
#if __has_builtin(__builtin_amdgcn_fdot2)
    return __builtin_amdgcn_fdot2(a, b, c, false);
#else
    return c + (float)a[0] * (float)b[0] + (float)a[1] * (float)b[1];
#endif
}

// ---------------- copy x -> hs0 ----------------
__global__ void k_copy(const float* __restrict__ x, float* __restrict__ hs0) {
    int i = blockIdx.x * 256 + threadIdx.x;           // 262144 float4
    ((float4*)hs0)[i] = ((const float4*)x)[i];
}

// ---------------- conv branches (merged) ----------------
__global__ __launch_bounds__(256) void k_conv2(
    const float* __restrict__ x,
    const float* __restrict__ cw5, const float* __restrict__ cb5,
    const float* __restrict__ cw7, const float* __restrict__ cb7,
    float* __restrict__ hs1, float* __restrict__ hs2) {
    extern __shared__ float S[];
    float* xt = S;              // [70][68]
    float* wl = S + 70 * 68;    // [(t*16+i4)*256 + o*4 + j]
    int b = blockIdx.x, wh = blockIdx.y, br = blockIdx.z;
    int K = br ? 7 : 5;
    const float* cw = br ? cw7 : cw5;
    const float* cb = br ? cb7 : cb5;
    float* dst = br ? hs2 : hs1;
    int w0 = wh * 64;
    int tid = threadIdx.x;

    for (int f = tid; f < 70 * 64; f += 256) {
        int ww = f >> 6, i = f & 63;
        int wp = w0 - 3 + ww;
        xt[ww * 68 + i] = ((unsigned)wp < 128u) ? x[b * 8192 + wp * 64 + i] : 0.f;
    }
    int nw = K * 4096;
    for (int f = tid; f < nw; f += 256) {
        int j = f & 3, o = (f >> 2) & 63, i4 = (f >> 8) & 15, t = f >> 12;
        wl[f] = cw[(o * 64 + i4 * 4 + j) * K + t];
    }
    __syncthreads();

    int to = tid & 15, tw = tid >> 4;
    float acc[4][4] = {};
    int ob = 3 - (K >> 1);
    for (int t = 0; t < K; ++t) {
        int rbase = tw * 4 + t + ob;
        for (int i4 = 0; i4 < 16; ++i4) {
            float4 a0 = *(const float4*)&xt[(rbase + 0) * 68 + i4 * 4];
            float4 a1 = *(const float4*)&xt[(rbase + 1) * 68 + i4 * 4];
            float4 a2 = *(const float4*)&xt[(rbase + 2) * 68 + i4 * 4];
            float4 a3 = *(const float4*)&xt[(rbase + 3) * 68 + i4 * 4];
            const float* wrow = &wl[(t * 16 + i4) * 256];
            float4 b0 = *(const float4*)&wrow[to * 4];
            float4 b1 = *(const float4*)&wrow[(to + 16) * 4];
            float4 b2 = *(const float4*)&wrow[(to + 32) * 4];
            float4 b3 = *(const float4*)&wrow[(to + 48) * 4];
            #define DOT4(w_, a_) \
                acc[w_][0] = fmaf(a_.x, b0.x, acc[w_][0]); acc[w_][0] = fmaf(a_.y, b0.y, acc[w_][0]); \
                acc[w_][0] = fmaf(a_.z, b0.z, acc[w_][0]); acc[w_][0] = fmaf(a_.w, b0.w, acc[w_][0]); \
                acc[w_][1] = fmaf(a_.x, b1.x, acc[w_][1]); acc[w_][1] = fmaf(a_.y, b1.y, acc[w_][1]); \
                acc[w_][1] = fmaf(a_.z, b1.z, acc[w_][1]); acc[w_][1] = fmaf(a_.w, b1.w, acc[w_][1]); \
                acc[w_][2] = fmaf(a_.x, b2.x, acc[w_][2]); acc[w_][2] = fmaf(a_.y, b2.y, acc[w_][2]); \
                acc[w_][2] = fmaf(a_.z, b2.z, acc[w_][2]); acc[w_][2] = fmaf(a_.w, b2.w, acc[w_][2]); \
                acc[w_][3] = fmaf(a_.x, b3.x, acc[w_][3]); acc[w_][3] = fmaf(a_.y, b3.y, acc[w_][3]); \
                acc[w_][3] = fmaf(a_.z, b3.z, acc[w_][3]); acc[w_][3] = fmaf(a_.w, b3.w, acc[w_][3]);
            DOT4(0, a0)
            DOT4(1, a1)
            DOT4(2, a2)
            DOT4(3, a3)
            #undef DOT4
        }
    }
    #pragma unroll
    for (int wj = 0; wj < 4; ++wj) {
        int w = w0 + tw * 4 + wj;
        #pragma unroll
        for (int oj = 0; oj < 4; ++oj) {
            int o = to + 16 * oj;
            dst[b * 8192 + w * 64 + o] = fmaxf(acc[wj][oj] + cb[o], 0.f);
        }
    }
}

// ---------------- one STGAT layer (all 3 branches), fp16 dot2, in-place residual ----------------
// grid (128 b, 3 br), block 256, dyn LDS 77824 B -> 2 blocks/CU
__global__ __launch_bounds__(256, 2) void k_stgat(
    float* __restrict__ hs0, float* __restrict__ hs1, float* __restrict__ hs2,
    const float* __restrict__ gat_w, const float* __restrict__ gat_asrc,
    const float* __restrict__ gat_adst, const float* __restrict__ gat_b,
    const float* __restrict__ gcn_w, const float* __restrict__ gcn_b, int l) {
    extern __shared__ float S[];
    _Float16* Sh = (_Float16*)S;
    // half-offsets
    const int XHh = 0;           // xp fp16 [64 n][132 w]      (stage, phase1)
    const int GHh = 8448;        // gw fp16 [128 wo][132 k]    (stage, phase1)
    const int HHTh = 25344;      // h^T fp16 [128 wo][68 n]    (phase1 -> 2b)
    const int AHh = 34560;       // A fp16 [64 j][68 i]        (2a -> 2b)
    const int FHh = 8448;        // f^T fp16 [128 w][68 n]     (2b -> 3b, overlays GH)
    const int CHh = 0;           // cw fp16 [64 c][68 k]       (2a -> 3b, overlays XH)
    // float-offsets
    const int SDo = 17024;       // s[64], d[64]               (phase1 -> 2a)
    const int CSo = 17024;       // chunk sums [4][64]         (3c, overlays SD)
    const int HGo = 8576;        // hg fp32 [128 w][66 c]      (3b -> 3d, overlays GH-tail+HHT)

    int b = blockIdx.x, br = blockIdx.y, tid = threadIdx.x;
    float* hs = (br == 0 ? hs0 : (br == 1 ? hs1 : hs2)) + b * 8192;
    int wsel = br * 2 + l;
    const float* gw = gat_w + wsel * 16384;
    const float* asr = gat_asrc + wsel * 128;
    const float* ads = gat_adst + wsel * 128;
    const float* gb = gat_b + wsel * 128;
    const float* cwp = gcn_w + wsel * 4096;
    const float* cbp = gcn_b + wsel * 64;

    // ---- stage: xp (4x4 microtile transpose) and gw, both fp16 ----
    {
        const float4* hsv = (const float4*)hs;
        for (int mt = tid; mt < 512; mt += 256) {
            int ng = mt & 15, wg = mt >> 4;
            float4 r0 = hsv[(wg * 4 + 0) * 16 + ng];
            float4 r1 = hsv[(wg * 4 + 1) * 16 + ng];
            float4 r2 = hsv[(wg * 4 + 2) * 16 + ng];
            float4 r3 = hsv[(wg * 4 + 3) * 16 + ng];
            int n0 = ng * 4, ww = wg * 4;
            *(uint2*)&Sh[XHh + (n0 + 0) * 132 + ww] = make_uint2(pku(r0.x, r1.x), pku(r2.x, r3.x));
            *(uint2*)&Sh[XHh + (n0 + 1) * 132 + ww] = make_uint2(pku(r0.y, r1.y), pku(r2.y, r3.y));
            *(uint2*)&Sh[XHh + (n0 + 2) * 132 + ww] = make_uint2(pku(r0.z, r1.z), pku(r2.z, r3.z));
            *(uint2*)&Sh[XHh + (n0 + 3) * 132 + ww] = make_uint2(pku(r0.w, r1.w), pku(r2.w, r3.w));
        }
        const float4* gwv = (const float4*)gw;
        for (int f4 = tid; f4 < 4096; f4 += 256) {
            float4 v = gwv[f4];
            int wo = f4 >> 5, k4 = f4 & 31;
            *(uint2*)&Sh[GHh + wo * 132 + k4 * 4] = make_uint2(pku(v.x, v.y), pku(v.z, v.w));
        }
    }
    __syncthreads();

    int wq = tid & 15, nq = tid >> 4;
    // ---- phase1: h[n][wo] = sum_k xp[n][k]*gw[wo][k]; store h^T; fused s/d dots ----
    {
        float asv[8], adv[8];
        #pragma unroll
        for (int c = 0; c < 8; ++c) { asv[c] = asr[wq + 16 * c]; adv[c] = ads[wq + 16 * c]; }
        float acc0[8] = {}, acc1[8] = {}, acc2[8] = {}, acc3[8] = {};
        const _Float16* Arow = Sh + XHh + nq * 4 * 132;
        const _Float16* Brow = Sh + GHh + wq * 132;
        for (int k4 = 0; k4 < 32; ++k4) {
            uint2 u0 = *(const uint2*)&Arow[k4 * 4];
            uint2 u1 = *(const uint2*)&Arow[132 + k4 * 4];
            uint2 u2 = *(const uint2*)&Arow[264 + k4 * 4];
            uint2 u3 = *(const uint2*)&Arow[396 + k4 * 4];
            v2h a0l = upk(u0.x), a0h = upk(u0.y), a1l = upk(u1.x), a1h = upk(u1.y);
            v2h a2l = upk(u2.x), a2h = upk(u2.y), a3l = upk(u3.x), a3h = upk(u3.y);
            #pragma unroll
            for (int c = 0; c < 8; ++c) {
                uint2 ub = *(const uint2*)&Brow[c * (16 * 132) + k4 * 4];
                v2h bl = upk(ub.x), bh = upk(ub.y);
                acc0[c] = fdot2(a0l, bl, acc0[c]); acc0[c] = fdot2(a0h, bh, acc0[c]);
                acc1[c] = fdot2(a1l, bl, acc1[c]); acc1[c] = fdot2(a1h, bh, acc1[c]);
                acc2[c] = fdot2(a2l, bl, acc2[c]); acc2[c] = fdot2(a2h, bh, acc2[c]);
                acc3[c] = fdot2(a3l, bl, acc3[c]); acc3[c] = fdot2(a3h, bh, acc3[c]);
            }
        }
        #pragma unroll
        for (int c = 0; c < 8; ++c)
            *(uint2*)&Sh[HHTh + (wq + 16 * c) * 68 + nq * 4] =
                make_uint2(pku(acc0[c], acc1[c]), pku(acc2[c], acc3[c]));
        float ps0 = 0, ps1 = 0, ps2 = 0, ps3 = 0, pd0 = 0, pd1 = 0, pd2 = 0, pd3 = 0;
        #pragma unroll
        for (int c = 0; c < 8; ++c) {
            ps0 = fmaf(acc0[c], asv[c], ps0); ps1 = fmaf(acc1[c], asv[c], ps1);
            ps2 = fmaf(acc2[c], asv[c], ps2); ps3 = fmaf(acc3[c], asv[c], ps3);
            pd0 = fmaf(acc0[c], adv[c], pd0); pd1 = fmaf(acc1[c], adv[c], pd1);
            pd2 = fmaf(acc2[c], adv[c], pd2); pd3 = fmaf(acc3[c], adv[c], pd3);
        }
        #pragma unroll
        for (int m = 1; m < 16; m <<= 1) {
            ps0 += __shfl_xor(ps0, m); ps1 += __shfl_xor(ps1, m);
            ps2 += __shfl_xor(ps2, m); ps3 += __shfl_xor(ps3, m);
            pd0 += __shfl_xor(pd0, m); pd1 += __shfl_xor(pd1, m);
            pd2 += __shfl_xor(pd2, m); pd3 += __shfl_xor(pd3, m);
        }
        if (wq == 0) {
            S[SDo + nq * 4 + 0] = ps0; S[SDo + nq * 4 + 1] = ps1;
            S[SDo + nq * 4 + 2] = ps2; S[SDo + nq * 4 + 3] = ps3;
            S[SDo + 64 + nq * 4 + 0] = pd0; S[SDo + 64 + nq * 4 + 1] = pd1;
            S[SDo + 64 + nq * 4 + 2] = pd2; S[SDo + 64 + nq * 4 + 3] = pd3;
        }
    }
    __syncthreads();

    // ---- phase2a: softmax rows -> AH fp16 ; concurrently stage gcn weights -> CH ----
    {
        const float4* cwv = (const float4*)cwp;
        for (int f4 = tid; f4 < 1024; f4 += 256) {
            float4 v = cwv[f4];
            int c = f4 >> 4, k4 = f4 & 15;
            *(uint2*)&Sh[CHh + c * 68 + k4 * 4] = make_uint2(pku(v.x, v.y), pku(v.z, v.w));
        }
        if (tid < 64) {
            int j = tid;
            float dj = S[SDo + 64 + j];
            float mx = -1e30f;
            for (int i = 0; i < 64; ++i) {
                float e = S[SDo + i] + dj;
                e = (e > 0.f) ? e : 0.2f * e;
                mx = fmaxf(mx, e);
            }
            float sum = 0.f;
            for (int i = 0; i < 64; i += 2) {
                float e0 = S[SDo + i] + dj;     e0 = (e0 > 0.f) ? e0 : 0.2f * e0;
                float e1 = S[SDo + i + 1] + dj; e1 = (e1 > 0.f) ? e1 : 0.2f * e1;
                float x0 = __expf(e0 - mx), x1 = __expf(e1 - mx);
                sum += x0 + x1;
                *(unsigned*)&Sh[AHh + j * 68 + i] = pku(x0, x1);
            }
            float rinv = 1.f / sum;
            for (int i = 0; i < 64; i += 2) {
                v2h v = upk(*(const unsigned*)&Sh[AHh + j * 68 + i]);
                *(unsigned*)&Sh[AHh + j * 68 + i] = pku((float)v[0] * rinv, (float)v[1] * rinv);
            }
        }
    }
    __syncthreads();

    // ---- phase2b: f[n][w] = sum_i A[n][i]*h[i][w] ; relu(+gb[w]); store f^T ----
    {
        float gbv[8];
        #pragma unroll
        for (int c = 0; c < 8; ++c) gbv[c] = gb[wq + 16 * c];
        float acc0[8] = {}, acc1[8] = {}, acc2[8] = {}, acc3[8] = {};
        const _Float16* Arow = Sh + AHh + nq * 4 * 68;
        const _Float16* Brow = Sh + HHTh + wq * 68;
        for (int k4 = 0; k4 < 16; ++k4) {
            uint2 u0 = *(const uint2*)&Arow[k4 * 4];
            uint2 u1 = *(const uint2*)&Arow[68 + k4 * 4];
            uint2 u2 = *(const uint2*)&Arow[136 + k4 * 4];
            uint2 u3 = *(const uint2*)&Arow[204 + k4 * 4];
            v2h a0l = upk(u0.x), a0h = upk(u0.y), a1l = upk(u1.x), a1h = upk(u1.y);
            v2h a2l = upk(u2.x), a2h = upk(u2.y), a3l = upk(u3.x), a3h = upk(u3.y);
            #pragma unroll
            for (int c = 0; c < 8; ++c) {
                uint2 ub = *(const uint2*)&Brow[c * (16 * 68) + k4 * 4];
                v2h bl = upk(ub.x), bh = upk(ub.y);
                acc0[c] = fdot2(a0l, bl, acc0[c]); acc0[c] = fdot2(a0h, bh, acc0[c]);
                acc1[c] = fdot2(a1l, bl, acc1[c]); acc1[c] = fdot2(a1h, bh, acc1[c]);
                acc2[c] = fdot2(a2l, bl, acc2[c]); acc2[c] = fdot2(a2h, bh, acc2[c]);
                acc3[c] = fdot2(a3l, bl, acc3[c]); acc3[c] = fdot2(a3h, bh, acc3[c]);
            }
        }
        #pragma unroll
        for (int c = 0; c < 8; ++c) {
            float f0 = fmaxf(acc0[c] + gbv[c], 0.f);
            float f1 = fmaxf(acc1[c] + gbv[c], 0.f);
            float f2 = fmaxf(acc2[c] + gbv[c], 0.f);
            float f3 = fmaxf(acc3[c] + gbv[c], 0.f);
            *(uint2*)&Sh[FHh + (wq + 16 * c) * 68 + nq * 4] = make_uint2(pku(f0, f1), pku(f2, f3));
        }
    }
    __syncthreads();

    // ---- phase3b: hg[w][c] = sum_k fT[w][k]*cw[c][k] (fp32 out) ----
    {
        int cq = tid & 7, wg = tid >> 3;
        float acc0[8] = {}, acc1[8] = {}, acc2[8] = {}, acc3[8] = {};
        const _Float16* Arow = Sh + FHh + wg * 4 * 68;
        const _Float16* Brow = Sh + CHh + cq * 68;
        for (int k4 = 0; k4 < 16; ++k4) {
            uint2 u0 = *(const uint2*)&Arow[k4 * 4];
            uint2 u1 = *(const uint2*)&Arow[68 + k4 * 4];
            uint2 u2 = *(const uint2*)&Arow[136 + k4 * 4];
            uint2 u3 = *(const uint2*)&Arow[204 + k4 * 4];
            v2h a0l = upk(u0.x), a0h = upk(u0.y), a1l = upk(u1.x), a1h = upk(u1.y);
            v2h a2l = upk(u2.x), a2h = upk(u2.y), a3l = upk(u3.x), a3h = upk(u3.y);
            #pragma unroll
            for (int cc = 0; cc < 8; ++cc) {
                uint2 ub = *(const uint2*)&Brow[cc * (8 * 68) + k4 * 4];
                v2h bl = upk(ub.x), bh = upk(ub.y);
                acc0[cc] = fdot2(a0l, bl, acc0[cc]); acc0[cc] = fdot2(a0h, bh, acc0[cc]);
                acc1[cc] = fdot2(a1l, bl, acc1[cc]); acc1[cc] = fdot2(a1h, bh, acc1[cc]);
                acc2[cc] = fdot2(a2l, bl, acc2[cc]); acc2[cc] = fdot2(a2h, bh, acc2[cc]);
                acc3[cc] = fdot2(a3l, bl, acc3[cc]); acc3[cc] = fdot2(a3h, bh, acc3[cc]);
            }
        }
        #pragma unroll
        for (int cc = 0; cc < 8; ++cc) {
            int c = cq + 8 * cc;
            S[HGo + (wg * 4 + 0) * 66 + c] = acc0[cc];
            S[HGo + (wg * 4 + 1) * 66 + c] = acc1[cc];
            S[HGo + (wg * 4 + 2) * 66 + c] = acc2[cc];
            S[HGo + (wg * 4 + 3) * 66 + c] = acc3[cc];
        }
    }
    __syncthreads();

    // ---- phase3c: chunked parallel prefix scan with dinv=rsqrt(w+1), +bias, relu ----
    {
        int c = tid & 63, q = tid >> 6;
        float local = 0.f;
        for (int i = 0; i < 32; ++i) {
            int w = q * 32 + i;
            local = fmaf(rsqrtf((float)(w + 1)), S[HGo + w * 66 + c], local);
        }
        S[CSo + q * 64 + c] = local;
    }
    __syncthreads();
    {
        int c = tid & 63, q = tid >> 6;
        float run = 0.f;
        for (int qq = 0; qq < q; ++qq) run += S[CSo + qq * 64 + c];
        float cbv = cbp[c];
        for (int i = 0; i < 32; ++i) {
            int w = q * 32 + i;
            float dv = rsqrtf((float)(w + 1));
            run = fmaf(dv, S[HGo + w * 66 + c], run);
            S[HGo + w * 66 + c] = fmaxf(fmaf(dv, run, cbv), 0.f);
        }
    }
    __syncthreads();

    // ---- phase3d: permuted residual, read-modify-write global hs ----
    {
        float4* hsv4 = (float4*)hs;
        for (int f4 = tid; f4 < 2048; f4 += 256) {
            int a = f4 >> 4, cc0 = (f4 & 15) * 4;
            float4 old = hsv4[f4];
            int n = a & 63, ahi = a >> 6;
            old.x += S[HGo + (cc0 * 2 + ahi) * 66 + n];
            old.y += S[HGo + ((cc0 + 1) * 2 + ahi) * 66 + n];
            old.z += S[HGo + ((cc0 + 2) * 2 + ahi) * 66 + n];
            old.w += S[HGo + ((cc0 + 3) * 2 + ahi) * 66 + n];
            hsv4[f4] = old;
        }
    }
}

// ---------------- encoder input GEMM (dir0 full) ----------------
__global__ __launch_bounds__(256) void k_encgemm(
    const float* __restrict__ hs0, const float* __restrict__ hs1, const float* __restrict__ hs2,
    const float* __restrict__ wih, const float* __restrict__ bih, const float* __restrict__ bhh,
    float* __restrict__ gx0) {
    __shared__ __align__(16) float At[32 * 132];
    __shared__ __align__(16) float Bt[32 * 68];
    int b = blockIdx.x, ny = blockIdx.y, tid = threadIdx.x;
    int g0 = ny * 64;
    int ty = tid >> 4, tx = tid & 15;
    float acc[8][4];
    #pragma unroll
    for (int r = 0; r < 8; ++r)
        #pragma unroll
        for (int c = 0; c < 4; ++c) acc[r][c] = 0.f;
    const float* hsb[3] = {hs0 + b * 8192, hs1 + b * 8192, hs2 + b * 8192};
    for (int kc = 0; kc < 6; ++kc) {
        const float* src = hsb[kc >> 1] + (kc & 1) * 32;
        for (int f = tid; f < 4096; f += 256) {
            int t = f >> 5, kk = f & 31;
            At[kk * 132 + t] = src[t * 64 + kk];
        }
        for (int f = tid; f < 2048; f += 256) {
            int gg = f >> 5, kk = f & 31;
            int g = g0 + gg;
            Bt[kk * 68 + gg] = (g < 600) ? wih[g * 192 + kc * 32 + kk] : 0.f;
        }
        __syncthreads();
        #pragma unroll 8
        for (int kk = 0; kk < 32; ++kk) {
            float a[8], bb[4];
            *(float4*)&a[0] = *(const float4*)&At[kk * 132 + ty * 8];
            *(float4*)&a[4] = *(const float4*)&At[kk * 132 + ty * 8 + 4];
            *(float4*)&bb[0] = *(const float4*)&Bt[kk * 68 + tx * 4];
            #pragma unroll
            for (int r = 0; r < 8; ++r)
                #pragma unroll
                for (int c = 0; c < 4; ++c) acc[r][c] = fmaf(a[r], bb[c], acc[r][c]);
        }
        __syncthreads();
    }
    for (int r = 0; r < 8; ++r) {
        int t = ty * 8 + r;
        for (int c = 0; c < 4; ++c) {
            int g = g0 + tx * 4 + c;
            if (g < 600) gx0[(b * 128 + t) * 600 + g] = acc[r][c] + bih[g] + bhh[g];
        }
    }
}

// ---------------- encoder dir1 gates at t=127 only ----------------
__global__ void k_encgx1(const float* __restrict__ hs0, const float* __restrict__ hs1,
                         const float* __restrict__ hs2, const float* __restrict__ wih,
                         const float* __restrict__ bih, const float* __restrict__ bhh,
                         float* __restrict__ gx1) {
    __shared__ __align__(16) float sh[192];
    int b = blockIdx.x, tid = threadIdx.x;
    if (tid < 192) {
        const float* src = (tid < 64 ? hs0 : (tid < 128 ? hs1 : hs2));
        sh[tid] = src[b * 8192 + 127 * 64 + (tid & 63)];
    }
    __syncthreads();
    const float* w1 = wih + 600 * 192;
    for (int g = tid; g < 600; g += 256) {
        float acc = bih[600 + g] + bhh[600 + g];
        const float4* wr = (const float4*)(w1 + g * 192);
        #pragma unroll 8
        for (int q = 0; q < 48; ++q) {
            float4 wv = wr[q];
            float4 hv = *(const float4*)&sh[q * 4];
            acc = fmaf(wv.x, hv.x, acc);
            acc = fmaf(wv.y, hv.y, acc);
            acc = fmaf(wv.z, hv.z, acc);
            acc = fmaf(wv.w, hv.w, acc);
        }
        gx1[b * 600 + g] = acc;
    }
}

// ---------------- prefix sums of dec_wih rows: PT[k][dg], k=0..300 ----------------
__global__ void k_ptpref(const float* __restrict__ dwih, float* __restrict__ PT) {
    int dg = blockIdx.x * 256 + threadIdx.x;
    if (dg >= 1200) return;
    const float* wr = dwih + dg * 300;
    float run = 0.f;
    PT[dg] = 0.f;
    for (int k = 0; k < 300; ++k) {
        run += wr[k];
        PT[(k + 1) * 1200 + dg] = run;
    }
}

// ---------------- PD[(dirt*600+g)*4 + seg] ----------------
__global__ void k_pd(const float* __restrict__ PT, float* __restrict__ PD) {
    int id = blockIdx.x * 256 + threadIdx.x;
    if (id >= 153600) return;                 // 2*128*600
    int g = id % 600;
    int tt = id / 600;
    int t = tt & 127, dir = tt >> 7;
    int dg = dir * 600 + g;
    int base = t * 300;
    int j0 = base >> 7;
    int ke1 = (j0 + 1) * 128 - base;
    int ke2 = ke1 + 128; ke2 = ke2 > 300 ? 300 : ke2;
    int ke3 = ke1 + 256; ke3 = ke3 > 300 ? 300 : ke3;
    float p1 = PT[ke1 * 1200 + dg];
    float p2 = PT[ke2 * 1200 + dg];
    float p3 = PT[ke3 * 1200 + dg];
    float p4 = PT[300 * 1200 + dg];
    float4 o = {p1, p2 - p1, p3 - p2, p4 - p3};
    *(float4*)&PD[id * 4] = o;
}

// ---------------- encoder LSTM: thread = one gate row; quad = one hidden unit ----------------
__global__ __launch_bounds__(640, 3) void k_enclstm(
    const float* __restrict__ gx0, const float* __restrict__ gx1,
    const float* __restrict__ whh, float* __restrict__ h_end) {
    int bid = blockIdx.x, t = threadIdx.x;
    if (bid >= 128) {  // one bwd step from zero state on x_{127}
        int b = bid - 128;
        if (t < 150) {
            float ai = gx1[b * 600 + t];
            float ag = gx1[b * 600 + 300 + t];
            float ao = gx1[b * 600 + 450 + t];
            float c = sigm(ai) * tanhfast(ag);
            h_end[b * 300 + 150 + t] = sigm(ao) * tanhfast(c);
        }
        return;
    }
    __shared__ __align__(16) _Float16 hbuf[2][152];
    int b = bid;
    bool on = t < 600;
    int j = t >> 2, g4 = t & 3;
    int grow = g4 * 150 + j;
    v2h wv[76];
    #pragma unroll
    for (int p = 0; p < 76; ++p) wv[p] = pk2(0.f, 0.f);
    if (on) {
        const float* r = whh + grow * 150;
        #pragma unroll
        for (int p = 0; p < 75; ++p) wv[p] = pk2(r[2 * p], r[2 * p + 1]);
    }
    for (int i = t; i < 304; i += 640) ((_Float16*)hbuf)[i] = (_Float16)0.f;
    float c = 0.f;
    float xc = on ? gx0[(b * 128) * 600 + grow] : 0.f;
    __syncthreads();
    for (int s = 0; s < 128; ++s) {
        float xn = (on && s < 127) ? gx0[(b * 128 + s + 1) * 600 + grow] : 0.f;
        float s0 = 0.f, s1 = 0.f, s2 = 0.f, s3 = 0.f;
        const float4* hp = (const float4*)hbuf[s & 1];
        #pragma unroll
        for (int cc = 0; cc < 19; ++cc) {
            float4 hv = hp[cc];
            s0 = fdot2(wv[4 * cc + 0], __builtin_bit_cast(v2h, hv.x), s0);
            s1 = fdot2(wv[4 * cc + 1], __builtin_bit_cast(v2h, hv.y), s1);
            s2 = fdot2(wv[4 * cc + 2], __builtin_bit_cast(v2h, hv.z), s2);
            s3 = fdot2(wv[4 * cc + 3], __builtin_bit_cast(v2h, hv.w), s3);
        }
        float a = xc + ((s0 + s1) + (s2 + s3));
        bool isg = (g4 == 2);
        float sg = sigm(isg ? 2.f * a : a);
        float act = isg ? fmaf(2.f, sg, -1.f) : sg;
        float vf = __shfl_xor(act, 1);
        float vg = __shfl_xor(act, 2);
        float vo = __shfl_xor(vf, 2);
        if (on && g4 == 0) {
            c = fmaf(vf, c, act * vg);
            float h = vo * tanhfast(c);
            hbuf[(s + 1) & 1][j] = (_Float16)h;
            if (s == 127) h_end[b * 300 + j] = h;
        }
        xc = xn;
        __syncthreads();
    }
}

// ---------------- decoder LSTM (both dirs), x-part via PD table ----------------
__global__ __launch_bounds__(640, 3) void k_declstm(
    const float* __restrict__ PD, const float* __restrict__ hend,
    const float* __restrict__ whh_all, const float* __restrict__ bih,
    const float* __restrict__ bhh, float* __restrict__ dec_out) {
    __shared__ __align__(16) float she[304];
    __shared__ __align__(16) _Float16 hbuf[2][152];
    int dir = blockIdx.x >> 7, b = blockIdx.x & 127;
    int t = threadIdx.x;
    bool on = t < 600;
    int j = t >> 2, g4 = t & 3;
    int grow = g4 * 150 + j;
    v2h wv[76];
    #pragma unroll
    for (int p = 0; p < 76; ++p) wv[p] = pk2(0.f, 0.f);
    float bias = 0.f;
    if (on) {
        const float* r = whh_all + dir * 90000 + grow * 150;
        #pragma unroll
        for (int p = 0; p < 75; ++p) wv[p] = pk2(r[2 * p], r[2 * p + 1]);
        bias = bih[dir * 600 + grow] + bhh[dir * 600 + grow];
    }
    for (int i = t; i < 304; i += 640) she[i] = (i < 300) ? hend[b * 300 + i] : 0.f;
    for (int i = t; i < 304; i += 640) ((_Float16*)hbuf)[i] = (_Float16)0.f;
    float c = 0.f;
    int t0 = dir ? 127 : 0;
    float4 pd = {0.f, 0.f, 0.f, 0.f};
    if (on) pd = *(const float4*)&PD[((dir * 128 + t0) * 600 + grow) * 4];
    __syncthreads();
    for (int s = 0; s < 128; ++s) {
        int tt = dir ? (127 - s) : s;
        float4 pdn = {0.f, 0.f, 0.f, 0.f};
        if (on && s < 127) {
            int tn = dir ? (126 - s) : (s + 1);
            pdn = *(const float4*)&PD[((dir * 128 + tn) * 600 + grow) * 4];
        }
        int j0 = (tt * 300) >> 7;
        float e0 = she[j0], e1 = she[j0 + 1], e2 = she[j0 + 2], e3 = she[j0 + 3];
        float a = bias + e0 * pd.x + e1 * pd.y + e2 * pd.z + e3 * pd.w;
        float s0 = 0.f, s1 = 0.f, s2 = 0.f, s3 = 0.f;
        const float4* hp = (const float4*)hbuf[s & 1];
        #pragma unroll
        for (int cc = 0; cc < 19; ++cc) {
            float4 hv = hp[cc];
            s0 = fdot2(wv[4 * cc + 0], __builtin_bit_cast(v2h, hv.x), s0);
            s1 = fdot2(wv[4 * cc + 1], __builtin_bit_cast(v2h, hv.y), s1);
            s2 = fdot2(wv[4 * cc + 2], __builtin_bit_cast(v2h, hv.z), s2);
            s3 = fdot2(wv[4 * cc + 3], __builtin_bit_cast(v2h, hv.w), s3);
        }
        a += (s0 + s1) + (s2 + s3);
        bool isg = (g4 == 2);
        float sg = sigm(isg ? 2.f * a : a);
        float act = isg ? fmaf(2.f, sg, -1.f) : sg;
        float vf = __shfl_xor(act, 1);
        float vg = __shfl_xor(act, 2);
        float vo = __shfl_xor(vf, 2);
        if (on && g4 == 0) {
            c = fmaf(vf, c, act * vg);
            float h = vo * tanhfast(c);
            hbuf[(s + 1) & 1][j] = (_Float16)h;
            dec_out[(b * 128 + tt) * 300 + dir * 150 + j] = h;
        }
        pd = pdn;
        __syncthreads();
    }
}

// ---------------- final: out = dec @ fc_w^T + fc_b ----------------
__global__ __launch_bounds__(256) void k_fingemm(const float* __restrict__ dec,
                                                 const float* __restrict__ fw,
                                                 const float* __restrict__ fb,
                                                 float* __restrict__ out) {
    __shared__ __align__(16) float AsT[32 * 68];
    __shared__ __align__(16) float FwT[32 * 68];
    int r0 = blockIdx.x * 64, tid = threadIdx.x;
    int ty = tid >> 4, tx = tid & 15;
    float acc[4][4];
    #pragma unroll
    for (int r = 0; r < 4; ++r)
        #pragma unroll
        for (int c = 0; c < 4; ++c) acc[r][c] = 0.f;
    for (int kc = 0; kc < 10; ++kc) {
        int k0 = kc * 32;
        for (int f = tid; f < 2048; f += 256) {
            int m = f >> 5, kk = f & 31;
            int k = k0 + kk;
            AsT[kk * 68 + m] = (k < 300) ? dec[(r0 + m) * 300 + k] : 0.f;
        }
        for (int f = tid; f < 2048; f += 256) {
            int n = f >> 5, kk = f & 31;
            int k = k0 + kk;
            FwT[kk * 68 + n] = (k < 300) ? fw[n * 300 + k] : 0.f;
        }
        __syncthreads();
        #pragma unroll 8
        for (int kk = 0; kk < 32; ++kk) {
            float a[4], w[4];
            *(float4*)&a[0] = *(const float4*)&AsT[kk * 68 + ty * 4];
            *(float4*)&w[0] = *(const float4*)&FwT[kk * 68 + tx * 4];
            #pragma unroll
            for (int r = 0; r < 4; ++r)
                #pragma unroll
                for (int c = 0; c < 4; ++c) acc[r][c] = fmaf(a[r], w[c], acc[r][c]);
        }
        __syncthreads();
    }
    for (int r = 0; r < 4; ++r) {
        int m = r0 + ty * 4 + r;
        float4 o4;
        o4.x = acc[r][0] + fb[tx * 4 + 0];
        o4.y = acc[r][1] + fb[tx * 4 + 1];
        o4.z = acc[r][2] + fb[tx * 4 + 2];
        o4.w = acc[r][3] + fb[tx * 4 + 3];
        *(float4*)&out[m * 64 + tx * 4] = o4;
    }
}

// ---------------- host launcher ----------------
extern "C" void kernel_launch(void* const* d_in, const int* in_sizes, int n_in,
                              void* d_out, int out_size, void* d_ws, size_t ws_size,
                              hipStream_t stream) {
    const float* x = (const float*)d_in[0];
    const float* c2w = (const float*)d_in[3];
    const float* c2b = (const float*)d_in[4];
    const float* c3w = (const float*)d_in[5];
    const float* c3b = (const float*)d_in[6];
    const float* gatw = (const float*)d_in[7];
    const float* gatas = (const float*)d_in[8];
    const float* gatad = (const float*)d_in[9];
    const float* gatb = (const float*)d_in[10];
    const float* gcnw = (const float*)d_in[11];
    const float* gcnb = (const float*)d_in[12];
    const float* lwih = (const float*)d_in[13];
    const float* lwhh = (const float*)d_in[14];
    const float* lbih = (const float*)d_in[15];
    const float* lbhh = (const float*)d_in[16];
    const float* dwih = (const float*)d_in[17];
    const float* dwhh = (const float*)d_in[18];
    const float* dbih = (const float*)d_in[19];
    const float* dbhh = (const float*)d_in[20];
    const float* fcw = (const float*)d_in[21];
    const float* fcb = (const float*)d_in[22];
    float* out = (float*)d_out;
    float* ws = (float*)d_ws;

    float* hs0 = ws;                    // 1,048,576
    float* hs1 = ws + 1048576;          // 1,048,576
    float* hs2 = ws + 2097152;          // 1,048,576
    float* gx0 = ws + 3145728;          // 9,830,400
    float* gx1 = ws + 12976128;         // 76,800
    float* hend = ws + 13052928;        // 38,400
    float* PT = ws + 13091328;          // 361,200
    float* dec = ws + 13452528;         // 4,915,200
    float* PD = hs0;                    // 614,400 — overlays hs0 (dead after encgemm/encgx1)

    k_copy<<<1024, 256, 0, stream>>>(x, hs0);
    k_conv2<<<dim3(128, 2, 2), 256, (70 * 68 + 7 * 16 * 256) * 4, stream>>>(
        x, c2w, c2b, c3w, c3b, hs1, hs2);
    for (int l = 0; l < 2; ++l)
        k_stgat<<<dim3(128, 3), 256, 77824, stream>>>(hs0, hs1, hs2, gatw, gatas,
                                                      gatad, gatb, gcnw, gcnb, l);
    k_encgemm<<<dim3(128, 10), 256, 0, stream>>>(hs0, hs1, hs2, lwih, lbih, lbhh, gx0);
    k_encgx1<<<128, 256, 0, stream>>>(hs0, hs1, hs2, lwih, lbih, lbhh, gx1);
    k_ptpref<<<5, 256, 0, stream>>>(dwih, PT);
    k_pd<<<600, 256, 0, stream>>>(PT, PD);   // after encgemm/encgx1: hs0 region now dead
    k_enclstm<<<256, 640, 0, stream>>>(gx0, gx1, lwhh, hend);
    k_declstm<<<256, 640, 0, stream>>>(PD, hend, dwhh, dbih, dbhh, dec);
    k_fingemm<<<256, 256, 0, stream>>>(dec, fcw, fcb, out);
}